// Round 8
// baseline (224352.271 us; speedup 1.0000x reference)
//
#include <hip/hip_runtime.h>

#define NBLK 256
#define NTHR 512

// ---------------- ws float offsets ----------------
#define OFF_PRE   0u            // [400][32][256]
#define OFF_PMT   3276800u      // [32][128][400]
#define OFF_GATT  4915200u      // [8][32][4096]
#define OFF_GDEC  5963776u      // [8][32][4096]
#define OFF_E     7012352u      // [32][400]
#define OFF_AH    7025152u
#define OFF_AC0   7057920u
#define OFF_AC1   7090688u
#define OFF_DH    7123456u
#define OFF_DC    7156224u
#define OFF_AW0   7188992u
#define OFF_AW1   7201792u
#define OFF_AWC0  7214592u
#define OFF_AWC1  7227392u
#define OFF_CTX0  7240192u
#define OFF_CTX1  7256576u
#define OFF_BAR   7272960u
#define WS_TOTAL  7272976u      // 29.1 MB

#define LDS_FLOATS 14976        // dec gates: 320*34 + 2*2048 = 59,904 B (< 64 KB)

__device__ __forceinline__ float sigm(float x){ return 1.f/(1.f+__expf(-x)); }
__device__ __forceinline__ float ftanh(float x){
  x = fminf(fmaxf(x,-15.f),15.f);
  float e = __expf(2.f*x);
  return (e-1.f)/(e+1.f);
}

typedef const __attribute__((address_space(1))) unsigned int* gas_t;
typedef __attribute__((address_space(3))) unsigned int* las_t;

// device-scope grid barrier (R3-proven); bar[0]=count, bar[1]=generation
__device__ __forceinline__ void gsync(unsigned* bar){
  __syncthreads();
  if (threadIdx.x==0){
    __threadfence();
    unsigned g = __hip_atomic_load(bar+1, __ATOMIC_ACQUIRE, __HIP_MEMORY_SCOPE_AGENT);
    unsigned arrived = __hip_atomic_fetch_add(bar, 1u, __ATOMIC_ACQ_REL, __HIP_MEMORY_SCOPE_AGENT);
    if (arrived == NBLK-1u){
      __hip_atomic_store(bar, 0u, __ATOMIC_RELAXED, __HIP_MEMORY_SCOPE_AGENT);
      __hip_atomic_fetch_add(bar+1, 1u, __ATOMIC_ACQ_REL, __HIP_MEMORY_SCOPE_AGENT);
    } else {
      while (__hip_atomic_load(bar+1, __ATOMIC_ACQUIRE, __HIP_MEMORY_SCOPE_AGENT) == g){
        __builtin_amdgcn_s_sleep(2);
      }
    }
  }
  __syncthreads();
}

// -------------------- precompute --------------------

__global__ void zero_kernel(float* p, unsigned n){
  unsigned i = blockIdx.x*256u + threadIdx.x;
  if (i<n) p[i]=0.f;
}

__global__ __launch_bounds__(256) void prenet_kernel(const float* __restrict__ mel_target,
    const float* __restrict__ W1, const float* __restrict__ W2, float* __restrict__ pre)
{
  __shared__ float din[80];
  __shared__ float h1[256];
  int blk = blockIdx.x;          // t*32 + b
  int t = blk >> 5, b = blk & 31;
  int tid = threadIdx.x;
  if (tid < 80) din[tid] = (t==0) ? 0.f : mel_target[b*32000 + tid*400 + (t-1)];
  __syncthreads();
  float s=0.f;
  for (int c=0;c<80;c++) s += din[c]*W1[c*256+tid];
  h1[tid] = fmaxf(s,0.f);
  __syncthreads();
  float s2=0.f;
  for (int c=0;c<256;c++) s2 += h1[c]*W2[c*256+tid];
  pre[(size_t)blk*256 + tid] = fmaxf(s2,0.f);
}

// pmT[b][a][t] = sum_d memory[b][t][d]*memory_W[d][a]
__global__ __launch_bounds__(128) void pm_kernel(const float* __restrict__ memory,
    const float* __restrict__ memory_W, float* __restrict__ pmT)
{
  __shared__ float mrow[512];
  int blk = blockIdx.x;          // b*400 + t
  int b = blk/400, t = blk - b*400;
  int tid = threadIdx.x;
  const float* src = memory + (size_t)blk*512;
  for (int i=tid;i<512;i+=128) mrow[i]=src[i];
  __syncthreads();
  float s=0.f;
  for (int d=0; d<512; d++) s += mrow[d]*memory_W[d*128+tid];
  pmT[(size_t)b*51200 + tid*400 + t] = s;
}

// -------------------- phase A/D: gates GEMM partials --------------------
// block (cb=bid&31, kh=bid>>5): cols cb*128..+128, k-slice kh*SLICE..+SLICE
// x staged [kk][34pad]; weights double-buffered 8KB tiles via global_load_lds.
template<int SLICE, int KIH>
__device__ __forceinline__ void gates_phase(
    float* sm,
    const float* x0, int n0, const float* x1, int n1, const float* x2, int n2,
    const float* Wih, const float* Whh, float* Gp)
{
  constexpr int NT = SLICE/16;
  float* xs = sm;                    // [SLICE][34]
  float* wbuf = sm + SLICE*34;       // [2][2048]
  const int tid = threadIdx.x;
  const int bid = blockIdx.x;
  const int cb = bid & 31;
  const int kh = bid >> 5;
  const int k_beg = kh*SLICE;
  const int n01 = n0+n1;
  for (int base=0; base<32*SLICE; base+=NTHR){
    int idx = base+tid;
    if (idx < 32*SLICE){
      int r = idx/SLICE, kk = idx - r*SLICE;
      int k = k_beg + kk;
      float v;
      if (k<n0) v = x0[r*n0+k];
      else if (k<n01) v = x1[r*n1+(k-n0)];
      else v = x2[r*n2+(k-n01)];
      xs[kk*34+r] = v;
    }
  }
  __syncthreads();
  const int wv = tid>>6, lane = tid&63;
  const int fb = wv*1024 + lane*16;      // byte offset within 8KB tile
  const int kk_l = fb>>9;                // k-row (512B per row of 128 cols)
  const int inner = fb & 511;
  const size_t colbB = (size_t)cb*512;

  auto STAGE = [&](int s){
    int k = k_beg + s*16 + kk_l;
    const char* row = (k<KIH) ? ((const char*)Wih + (size_t)k*16384)
                              : ((const char*)Whh + (size_t)(k-KIH)*16384);
    const char* g = row + colbB + inner;
    float* l = &wbuf[(s&1)*2048 + wv*256];
    __builtin_amdgcn_global_load_lds((gas_t)g, (las_t)l, 16, 0, 0);
  };
  STAGE(0);
  const int rg = tid>>5, cg = tid&31;
  const int r0 = rg*2;
  float4 a0={0,0,0,0}, a1={0,0,0,0};
  for (int s=0; s<NT; s++){
    if (s+1<NT){
      STAGE(s+1);
      asm volatile("s_waitcnt vmcnt(1)" ::: "memory");
    } else {
      asm volatile("s_waitcnt vmcnt(0)" ::: "memory");
    }
    asm volatile("s_barrier" ::: "memory");
    const float* wb = wbuf + (s&1)*2048;
    const float* xk = xs + (s*16)*34;
    #pragma unroll
    for (int kk=0; kk<16; kk++){
      float4 w = *(const float4*)(wb + kk*128 + cg*4);
      float2 xv = *(const float2*)(xk + kk*34 + r0);
      a0.x += xv.x*w.x; a0.y += xv.x*w.y; a0.z += xv.x*w.z; a0.w += xv.x*w.w;
      a1.x += xv.y*w.x; a1.y += xv.y*w.y; a1.z += xv.y*w.z; a1.w += xv.y*w.w;
    }
    asm volatile("s_barrier" ::: "memory");
  }
  float* gp = Gp + (size_t)kh*131072 + cb*128 + cg*4;
  *(float4*)(gp + (size_t)(r0  )*4096) = a0;
  *(float4*)(gp + (size_t)(r0+1)*4096) = a1;
}

// -------------------- phase B: att middle (b=bid&31, yD=bid>>5) --------------------
__device__ __forceinline__ void att_mid_phase(
    float* sm, const float* Gp, const float* att_b,
    float* AH, const float* ACr, float* ACw,
    const float* query_W, const float* wcv, const float* wdv, const float* vvec,
    const float* pmT, const int* mlen,
    const float* AWr, const float* AWCr, float* E,
    const float* Gd, const float* dec_b, float* DH, float* DC, int step)
{
  float* ah_s = sm;          // 1024
  float* wd_s = sm+1024;     // 4096
  float* wc_s = sm+5120;     // 1984
  float* aw_s = sm+7104;     // 400
  float* awc_s= sm+7504;     // 400
  float* v_s  = sm+7904;     // 128
  float* q_s  = sm+8032;     // 128
  float* pool = sm+8160;     // 4608 (16B aligned: 8160*4=32640)
  const int bid = blockIdx.x, tid = threadIdx.x;
  const int b = bid & 31, yD = bid >> 5;

  for (int i=tid;i<400;i+=NTHR){ aw_s[i]=AWr[b*400+i]; awc_s[i]=AWCr[b*400+i]; }
  for (int i=tid;i<4096;i+=NTHR) wd_s[i]=wdv[i];
  for (int i=tid;i<1984;i+=NTHR) wc_s[i]=wcv[i];
  if (tid<128) v_s[tid]=vvec[tid];

  // reduce att gate partials (8 slices)
  {
    float4* g4 = (float4*)pool;
    for (int i=tid; i<1024; i+=NTHR){
      float4 s = {0,0,0,0};
      #pragma unroll
      for (int sl=0; sl<8; sl++){
        const float4* gs = (const float4*)(Gp + (size_t)sl*131072 + (size_t)b*4096);
        float4 v = gs[i];
        s.x+=v.x; s.y+=v.y; s.z+=v.z; s.w+=v.w;
      }
      g4[i] = s;
    }
  }
  __syncthreads();
  // att LSTM pointwise (redundant; yD==0 writes state)
  for (int u0=0; u0<2; u0++){
    int u = tid + u0*NTHR;
    float gi=pool[u]+att_b[u], gf=pool[1024+u]+att_b[1024+u];
    float gg=pool[2048+u]+att_b[2048+u], go=pool[3072+u]+att_b[3072+u];
    float c = sigm(gf)*ACr[b*1024+u] + sigm(gi)*ftanh(gg);
    float h = sigm(go)*ftanh(c);
    ah_s[u]=h;
    if (yD==0){ ACw[b*1024+u]=c; AH[b*1024+u]=h; }
  }
  __syncthreads();
  // q = ah @ query_W (4-way K split), qp in pool[0..512)
  { int a = tid & 127, sl = tid >> 7;
    float s=0.f; int kb = sl*256;
    for (int k=kb;k<kb+256;k++) s += ah_s[k]*query_W[k*128+a];
    pool[sl*128+a]=s; }
  __syncthreads();
  if (tid<128) q_s[tid] = pool[tid]+pool[128+tid]+pool[256+tid]+pool[384+tid];
  // distributed dec pointwise of step t-1 (units yD*128..+128)
  if (step>0 && tid<128){
    int u = yD*128 + tid;
    float gi=dec_b[u], gf=dec_b[1024+u], gg=dec_b[2048+u], go=dec_b[3072+u];
    #pragma unroll
    for (int sl=0; sl<8; sl++){
      const float* g = Gd + (size_t)sl*131072 + (size_t)b*4096;
      gi+=g[u]; gf+=g[1024+u]; gg+=g[2048+u]; go+=g[3072+u];
    }
    float c = sigm(gf)*DC[b*1024+u] + sigm(gi)*ftanh(gg);
    float h = sigm(go)*ftanh(c);
    DC[b*1024+u]=c; DH[b*1024+u]=h;
  }
  __syncthreads();
  // conv location features for chunk (50 t)
  const int t0 = yD*50;
  float* loc = pool + 512;   // 50*33
  { int tl = tid & 63, fs = tid >> 6;
    if (tl < 50){
      float cf0=0,cf1=0,cf2=0,cf3=0;
      int f0 = fs*4;
      int tg = t0 + tl;
      for (int k=0;k<31;k++){
        int gi2 = tg + k - 15;
        float a1 = (gi2>=0 && gi2<400) ? aw_s[gi2] : 0.f;
        float a2 = (gi2>=0 && gi2<400) ? awc_s[gi2] : 0.f;
        cf0 += wc_s[(f0+0)*62+k]*a1 + wc_s[(f0+0)*62+31+k]*a2;
        cf1 += wc_s[(f0+1)*62+k]*a1 + wc_s[(f0+1)*62+31+k]*a2;
        cf2 += wc_s[(f0+2)*62+k]*a1 + wc_s[(f0+2)*62+31+k]*a2;
        cf3 += wc_s[(f0+3)*62+k]*a1 + wc_s[(f0+3)*62+31+k]*a2;
      }
      loc[tl*33+f0+0]=cf0; loc[tl*33+f0+1]=cf1;
      loc[tl*33+f0+2]=cf2; loc[tl*33+f0+3]=cf3;
    }
  }
  __syncthreads();
  // energies for chunk
  float* ep = pool + 2176;   // 8*64
  { int tl = tid & 63, as = tid >> 6;
    if (tl < 50){
      int tg = t0 + tl;
      float e = 0.f;
      const float* lrow = loc + tl*33;
      for (int aa=0; aa<16; aa++){
        int a = as*16 + aa;
        float pmv = pmT[(size_t)b*51200 + (size_t)a*400 + tg];
        float lv = 0.f;
        #pragma unroll
        for (int f=0; f<32; f++) lv += lrow[f]*wd_s[f*128+a];
        e += ftanh(q_s[a]+pmv+lv)*v_s[a];
      }
      ep[as*64+tl] = e;
    }
  }
  __syncthreads();
  if (tid < 50){
    int tg = t0 + tid;
    float ee=0.f;
    #pragma unroll
    for (int as2=0; as2<8; as2++) ee += ep[as2*64+tid];
    E[b*400+tg] = (tg < mlen[b]) ? ee : -1e30f;
  }
}

// -------------------- phase C: softmax + ctx + proj(t-1) --------------------
__device__ __forceinline__ void softmax_ctx_phase(
    float* sm, const float* E, const float* memory,
    float* AWw, const float* AWCr, float* AWCw,
    float* CTXw, const float* CTXpp, const float* DH,
    const float* proj_W, const float* proj_b,
    const float* gate_W, const float* gate_b,
    float* out, float* aligns, int step)
{
  float* e_s = sm;           // 400
  float* red = sm+400;       // 16
  float* cp  = sm+416;       // 512
  float* do_s= sm+928;       // 1536
  float* pps = sm+2464;      // 486
  const int bid = blockIdx.x, tid = threadIdx.x;
  const int b = bid & 31, yD = bid >> 5;

  float ev = (tid<400) ? E[b*400+tid] : -1e30f;
  float m = ev;
  for (int off=32; off>0; off>>=1) m = fmaxf(m, __shfl_down(m, off, 64));
  if ((tid&63)==0) red[tid>>6]=m;
  __syncthreads();
  if (tid==0){ float mm=red[0]; for (int i=1;i<8;i++) mm=fmaxf(mm,red[i]); red[8]=mm; }
  __syncthreads();
  m = red[8];
  float ex = (tid<400) ? __expf(ev-m) : 0.f;
  float ss = ex;
  for (int off=32; off>0; off>>=1) ss += __shfl_down(ss, off, 64);
  if ((tid&63)==0) red[tid>>6]=ss;
  __syncthreads();
  if (tid==0){ float s2=0.f; for (int i=0;i<8;i++) s2+=red[i]; red[9]=1.f/s2; }
  __syncthreads();
  float anew = ex*red[9];
  if (tid<400) e_s[tid]=anew;
  if (yD==0 && tid<400){
    AWw[b*400+tid] = anew;
    AWCw[b*400+tid] = AWCr[b*400+tid] + anew;
    aligns[(size_t)b*160000 + (size_t)step*400 + tid] = anew;
  }
  __syncthreads();
  // ctx chunk
  { int d = tid & 63, ts = tid >> 6;
    const int d0 = yD*64;
    const float* mrow = memory + (size_t)b*204800 + d0 + d;
    float pacc=0.f;
    for (int tt=ts*50; tt<ts*50+50; tt++) pacc += e_s[tt]*mrow[(size_t)tt*512];
    cp[ts*64+d]=pacc; }
  __syncthreads();
  if (tid<64){
    float s2=0.f;
    #pragma unroll
    for (int ts2=0; ts2<8; ts2++) s2+=cp[ts2*64+tid];
    CTXw[b*512 + yD*64 + tid]=s2;
  }
  // projections for step-1 (yD==0 only)
  if (yD==0 && step>0){
    for (int i=tid; i<1536; i+=NTHR)
      do_s[i] = (i<1024) ? DH[b*1024+i] : CTXpp[b*512 + (i-1024)];
    __syncthreads();
    int sl = tid/81, o = tid - sl*81;
    if (sl < 6){
      float s=0.f; int kb = sl*256;
      for (int k=kb;k<kb+256;k++){
        float w2 = (o<80) ? proj_W[k*80+o] : gate_W[k];
        s += do_s[k]*w2;
      }
      pps[sl*81+o]=s;
    }
    __syncthreads();
    if (tid<81){
      float r=0.f;
      #pragma unroll
      for (int s2=0;s2<6;s2++) r += pps[s2*81+tid];
      if (tid<80) out[(size_t)b*32000 + tid*400 + (step-1)] = r + proj_b[tid];
      else        out[1024000 + b*400 + (step-1)] = r + gate_b[0];
    }
  }
}

// -------------------- epilogue: dec step 399 --------------------
__device__ __forceinline__ void dec_final_phase(
    float* sm, const float* Gd, const float* dec_b,
    const float* DC, const float* CTX1,
    const float* proj_W, const float* proj_b,
    const float* gate_W, const float* gate_b, float* out)
{
  float* g_s = sm;       // 4096
  float* do_s= sm+4096;  // 1536
  float* pps = sm+5632;  // 486
  const int b = blockIdx.x, tid = threadIdx.x;
  { float4* g4 = (float4*)g_s;
    for (int i=tid; i<1024; i+=NTHR){
      float4 s={0,0,0,0};
      #pragma unroll
      for (int sl=0; sl<8; sl++){
        const float4* gs = (const float4*)(Gd + (size_t)sl*131072 + (size_t)b*4096);
        float4 v = gs[i];
        s.x+=v.x; s.y+=v.y; s.z+=v.z; s.w+=v.w;
      }
      g4[i]=s;
    } }
  __syncthreads();
  for (int u0=0; u0<2; u0++){
    int u = tid + u0*NTHR;
    float gi=g_s[u]+dec_b[u], gf=g_s[1024+u]+dec_b[1024+u];
    float gg=g_s[2048+u]+dec_b[2048+u], go=g_s[3072+u]+dec_b[3072+u];
    float c = sigm(gf)*DC[b*1024+u] + sigm(gi)*ftanh(gg);
    do_s[u] = sigm(go)*ftanh(c);
  }
  do_s[1024+tid] = CTX1[b*512+tid];
  __syncthreads();
  int sl = tid/81, o = tid - sl*81;
  if (sl < 6){
    float s=0.f; int kb = sl*256;
    for (int k=kb;k<kb+256;k++){
      float w2 = (o<80) ? proj_W[k*80+o] : gate_W[k];
      s += do_s[k]*w2;
    }
    pps[sl*81+o]=s;
  }
  __syncthreads();
  if (tid<81){
    float r=0.f;
    #pragma unroll
    for (int s2=0;s2<6;s2++) r += pps[s2*81+tid];
    if (tid<80) out[(size_t)b*32000 + tid*400 + 399] = r + proj_b[tid];
    else        out[1024000 + b*400 + 399] = r + gate_b[0];
  }
}

// -------------------- the persistent cooperative kernel --------------------
__global__ void __launch_bounds__(NTHR) decoder_persist(
    const float* memory, const int* mlen, const float* query_W,
    const float* wcv, const float* wdv, const float* vvec,
    const float* att_Wih, const float* att_Whh, const float* att_b,
    const float* dec_Wih, const float* dec_Whh, const float* dec_b,
    const float* proj_W, const float* proj_b,
    const float* gate_W, const float* gate_b,
    float* ws, float* out)
{
  extern __shared__ float sm[];
  float* PRE  = ws + OFF_PRE;
  float* PMT  = ws + OFF_PMT;
  float* GATT = ws + OFF_GATT;
  float* GDEC = ws + OFF_GDEC;
  float* E    = ws + OFF_E;
  float* AH   = ws + OFF_AH;
  float* AC_[2] = { ws + OFF_AC0, ws + OFF_AC1 };
  float* DH   = ws + OFF_DH;
  float* DC   = ws + OFF_DC;
  float* AW_[2] = { ws + OFF_AW0, ws + OFF_AW1 };
  float* AWC_[2]= { ws + OFF_AWC0, ws + OFF_AWC1 };
  float* CTX_[2]= { ws + OFF_CTX0, ws + OFF_CTX1 };
  unsigned* bar = (unsigned*)(ws + OFF_BAR);
  float* aligns = out + 1036800;

  for (int t=0; t<400; t++){
    const int p = t & 1, pp = 1 - p;
    // A: att gates partials (K=1792 = 8 slices of 224)
    gates_phase<224,768>(sm, PRE + (size_t)t*8192, 256, CTX_[pp], 512, AH, 1024,
                         att_Wih, att_Whh, GATT);
    gsync(bar);
    // B: att reduce+pw+q+conv+energies + dec-pw(t-1)
    att_mid_phase(sm, GATT, att_b, AH, AC_[pp], AC_[p], query_W, wcv, wdv, vvec,
                  PMT, mlen, AW_[pp], AWC_[pp], E, GDEC, dec_b, DH, DC, t);
    gsync(bar);
    // C: softmax + ctx + proj(t-1)
    softmax_ctx_phase(sm, E, memory, AW_[p], AWC_[pp], AWC_[p], CTX_[p], CTX_[pp],
                      DH, proj_W, proj_b, gate_W, gate_b, out, aligns, t);
    gsync(bar);
    // D: dec gates partials (K=2560 = 8 slices of 320)
    gates_phase<320,1536>(sm, AH, 1024, CTX_[p], 512, DH, 1024,
                          dec_Wih, dec_Whh, GDEC);
    gsync(bar);
  }
  if (blockIdx.x < 32)
    dec_final_phase(sm, GDEC, dec_b, DC, CTX_[1], proj_W, proj_b, gate_W, gate_b, out);
}

// -------------------- launch --------------------

extern "C" void kernel_launch(void* const* d_in, const int* in_sizes, int n_in,
                              void* d_out, int out_size, void* d_ws, size_t ws_size,
                              hipStream_t stream) {
  const float* memory      = (const float*)d_in[0];
  const float* mel_target  = (const float*)d_in[1];
  const int*   mlen        = (const int*)  d_in[2];
  const float* prenet_W1   = (const float*)d_in[3];
  const float* prenet_W2   = (const float*)d_in[4];
  const float* query_W     = (const float*)d_in[5];
  const float* memory_W    = (const float*)d_in[6];
  const float* weight_vec  = (const float*)d_in[7];
  const float* loc_conv_W  = (const float*)d_in[8];
  const float* loc_dense_W = (const float*)d_in[9];
  const float* att_Wih     = (const float*)d_in[10];
  const float* att_Whh     = (const float*)d_in[11];
  const float* att_b       = (const float*)d_in[12];
  const float* dec_Wih     = (const float*)d_in[13];
  const float* dec_Whh     = (const float*)d_in[14];
  const float* dec_b       = (const float*)d_in[15];
  const float* proj_W      = (const float*)d_in[16];
  const float* proj_b      = (const float*)d_in[17];
  const float* gate_W      = (const float*)d_in[18];
  const float* gate_b      = (const float*)d_in[19];
  float* out = (float*)d_out;
  float* ws  = (float*)d_ws;

  float* PRE = ws + OFF_PRE;
  float* PMT = ws + OFF_PMT;

  // zero the entire used workspace every call -> replay-deterministic
  hipLaunchKernelGGL(zero_kernel, dim3((WS_TOTAL+255u)/256u), dim3(256), 0, stream, ws, WS_TOTAL);
  hipLaunchKernelGGL(prenet_kernel, dim3(12800), dim3(256), 0, stream,
                     mel_target, prenet_W1, prenet_W2, PRE);
  hipLaunchKernelGGL(pm_kernel, dim3(12800), dim3(128), 0, stream, memory, memory_W, PMT);

  void* args[] = {
    (void*)&memory, (void*)&mlen, (void*)&query_W,
    (void*)&loc_conv_W, (void*)&loc_dense_W, (void*)&weight_vec,
    (void*)&att_Wih, (void*)&att_Whh, (void*)&att_b,
    (void*)&dec_Wih, (void*)&dec_Whh, (void*)&dec_b,
    (void*)&proj_W, (void*)&proj_b, (void*)&gate_W, (void*)&gate_b,
    (void*)&ws, (void*)&out
  };
  hipLaunchCooperativeKernel((const void*)decoder_persist, dim3(NBLK), dim3(NTHR),
                             args, LDS_FLOATS*sizeof(float), stream);
}

// Round 9
// 136545.422 us; speedup vs baseline: 1.6431x; 1.6431x over previous
//
#include <hip/hip_runtime.h>

#define NBLK 256
#define NTHR 512

// ---------------- ws float offsets ----------------
#define OFF_PRE   0u            // [400][32][256]
#define OFF_PMT   3276800u      // [32][128][400]
#define OFF_GATT  4915200u      // [8][32][4096]
#define OFF_GDEC  5963776u      // [8][32][4096]
#define OFF_E     7012352u      // [32][400]
#define OFF_AH    7025152u
#define OFF_AC0   7057920u
#define OFF_AC1   7090688u
#define OFF_DH    7123456u
#define OFF_DC    7156224u
#define OFF_AW0   7188992u
#define OFF_AW1   7201792u
#define OFF_AWC0  7214592u
#define OFF_AWC1  7227392u
#define OFF_CTX0  7240192u
#define OFF_CTX1  7256576u
#define OFF_BAR   7272960u
#define WS_TOTAL  7272976u      // 29.1 MB

#define LDS_FLOATS 14976        // dec gates: 320*34 + 2*2048 floats = 59,904 B

__device__ __forceinline__ float sigm(float x){ return 1.f/(1.f+__expf(-x)); }
__device__ __forceinline__ float ftanh(float x){
  x = fminf(fmaxf(x,-15.f),15.f);
  float e = __expf(2.f*x);
  return (e-1.f)/(e+1.f);
}

typedef const __attribute__((address_space(1))) unsigned int* gas_t;
typedef __attribute__((address_space(3))) unsigned int* las_t;

// ---- SYSTEM-scope relaxed accessors: bypass L2 (sc0 sc1), no fences ----
__device__ __forceinline__ float ldf(const float* p){
  return __hip_atomic_load((const float*)p, __ATOMIC_RELAXED, __HIP_MEMORY_SCOPE_SYSTEM);
}
__device__ __forceinline__ void stf(float* p, float v){
  __hip_atomic_store(p, v, __ATOMIC_RELAXED, __HIP_MEMORY_SCOPE_SYSTEM);
}
__device__ __forceinline__ float2 ldf2(const float* p){
  unsigned long long u = __hip_atomic_load((const unsigned long long*)p,
      __ATOMIC_RELAXED, __HIP_MEMORY_SCOPE_SYSTEM);
  union{ unsigned long long u; float2 f; } c; c.u=u; return c.f;
}
__device__ __forceinline__ void stf2(float* p, float2 v){
  union{ unsigned long long u; float2 f; } c; c.f=v;
  __hip_atomic_store((unsigned long long*)p, c.u,
      __ATOMIC_RELAXED, __HIP_MEMORY_SCOPE_SYSTEM);
}

// fence-free grid barrier: relaxed system atomics only, explicit vmcnt discipline
__device__ __forceinline__ void gsync(unsigned* bar){
  asm volatile("s_waitcnt vmcnt(0)" ::: "memory");   // each wave: sys-stores visible
  __syncthreads();
  if (threadIdx.x==0){
    unsigned g = __hip_atomic_load(bar+1, __ATOMIC_RELAXED, __HIP_MEMORY_SCOPE_SYSTEM);
    unsigned arrived = __hip_atomic_fetch_add(bar, 1u, __ATOMIC_RELAXED, __HIP_MEMORY_SCOPE_SYSTEM);
    if (arrived == NBLK-1u){
      __hip_atomic_store(bar, 0u, __ATOMIC_RELAXED, __HIP_MEMORY_SCOPE_SYSTEM);
      asm volatile("s_waitcnt vmcnt(0)" ::: "memory");  // reset visible before gen bump
      __hip_atomic_fetch_add(bar+1, 1u, __ATOMIC_RELAXED, __HIP_MEMORY_SCOPE_SYSTEM);
    } else {
      while (__hip_atomic_load(bar+1, __ATOMIC_RELAXED, __HIP_MEMORY_SCOPE_SYSTEM) == g){
        __builtin_amdgcn_s_sleep(2);
      }
    }
  }
  __syncthreads();
}

// -------------------- precompute --------------------

__global__ void zero_kernel(float* p, unsigned n){
  unsigned i = blockIdx.x*256u + threadIdx.x;
  if (i<n) p[i]=0.f;
}

__global__ __launch_bounds__(256) void prenet_kernel(const float* __restrict__ mel_target,
    const float* __restrict__ W1, const float* __restrict__ W2, float* __restrict__ pre)
{
  __shared__ float din[80];
  __shared__ float h1[256];
  int blk = blockIdx.x;          // t*32 + b
  int t = blk >> 5, b = blk & 31;
  int tid = threadIdx.x;
  if (tid < 80) din[tid] = (t==0) ? 0.f : mel_target[b*32000 + tid*400 + (t-1)];
  __syncthreads();
  float s=0.f;
  for (int c=0;c<80;c++) s += din[c]*W1[c*256+tid];
  h1[tid] = fmaxf(s,0.f);
  __syncthreads();
  float s2=0.f;
  for (int c=0;c<256;c++) s2 += h1[c]*W2[c*256+tid];
  pre[(size_t)blk*256 + tid] = fmaxf(s2,0.f);
}

// pmT[b][a][t] = sum_d memory[b][t][d]*memory_W[d][a]
__global__ __launch_bounds__(128) void pm_kernel(const float* __restrict__ memory,
    const float* __restrict__ memory_W, float* __restrict__ pmT)
{
  __shared__ float mrow[512];
  int blk = blockIdx.x;          // b*400 + t
  int b = blk/400, t = blk - b*400;
  int tid = threadIdx.x;
  const float* src = memory + (size_t)blk*512;
  for (int i=tid;i<512;i+=128) mrow[i]=src[i];
  __syncthreads();
  float s=0.f;
  for (int d=0; d<512; d++) s += mrow[d]*memory_W[d*128+tid];
  pmT[(size_t)b*51200 + tid*400 + t] = s;
}

// -------------------- phase A/D: gates GEMM partials --------------------
// block (cb=bid&31, kh=bid>>5). Weights: normal cached loads via global_load_lds
// (L2-resident across steps). x + Gp partials: system-scope (mutable).
template<int SLICE, int KIH>
__device__ __forceinline__ void gates_phase(
    float* sm,
    const float* x0, int n0, const float* x1, int n1, const float* x2, int n2,
    const float* Wih, const float* Whh, float* Gp)
{
  constexpr int NT = SLICE/16;
  float* xs = sm;                    // [SLICE][34]
  float* wbuf = sm + SLICE*34;       // [2][2048]
  const int tid = threadIdx.x;
  const int bid = blockIdx.x;
  const int cb = bid & 31;
  const int kh = bid >> 5;
  const int k_beg = kh*SLICE;
  const int n01 = n0+n1;
  for (int base=0; base<32*SLICE; base+=NTHR){
    int idx = base+tid;
    if (idx < 32*SLICE){
      int r = idx/SLICE, kk = idx - r*SLICE;
      int k = k_beg + kk;
      float v;
      if (k<n0) v = ldf(x0 + r*n0+k);
      else if (k<n01) v = ldf(x1 + r*n1+(k-n0));
      else v = ldf(x2 + r*n2+(k-n01));
      xs[kk*34+r] = v;
    }
  }
  __syncthreads();
  const int wv = tid>>6, lane = tid&63;
  const int fb = wv*1024 + lane*16;      // byte offset within 8KB tile
  const int kk_l = fb>>9;                // k-row (512B per row of 128 cols)
  const int inner = fb & 511;
  const size_t colbB = (size_t)cb*512;

  auto STAGE = [&](int s){
    int k = k_beg + s*16 + kk_l;
    const char* row = (k<KIH) ? ((const char*)Wih + (size_t)k*16384)
                              : ((const char*)Whh + (size_t)(k-KIH)*16384);
    const char* g = row + colbB + inner;
    float* l = &wbuf[(s&1)*2048 + wv*256];
    __builtin_amdgcn_global_load_lds((gas_t)g, (las_t)l, 16, 0, 0);
  };
  STAGE(0);
  const int rg = tid>>5, cg = tid&31;
  const int r0 = rg*2;
  float4 a0={0,0,0,0}, a1={0,0,0,0};
  for (int s=0; s<NT; s++){
    if (s+1<NT){
      STAGE(s+1);
      asm volatile("s_waitcnt vmcnt(1)" ::: "memory");
    } else {
      asm volatile("s_waitcnt vmcnt(0)" ::: "memory");
    }
    asm volatile("s_barrier" ::: "memory");
    const float* wb = wbuf + (s&1)*2048;
    const float* xk = xs + (s*16)*34;
    #pragma unroll
    for (int kk=0; kk<16; kk++){
      float4 w = *(const float4*)(wb + kk*128 + cg*4);
      float2 xv = *(const float2*)(xk + kk*34 + r0);
      a0.x += xv.x*w.x; a0.y += xv.x*w.y; a0.z += xv.x*w.z; a0.w += xv.x*w.w;
      a1.x += xv.y*w.x; a1.y += xv.y*w.y; a1.z += xv.y*w.z; a1.w += xv.y*w.w;
    }
    asm volatile("s_barrier" ::: "memory");
  }
  float* gp = Gp + (size_t)kh*131072 + cb*128 + cg*4;
  stf2(gp + (size_t)(r0  )*4096,     make_float2(a0.x,a0.y));
  stf2(gp + (size_t)(r0  )*4096 + 2, make_float2(a0.z,a0.w));
  stf2(gp + (size_t)(r0+1)*4096,     make_float2(a1.x,a1.y));
  stf2(gp + (size_t)(r0+1)*4096 + 2, make_float2(a1.z,a1.w));
}

// -------------------- phase B: att middle (b=bid&31, yD=bid>>5) --------------------
__device__ __forceinline__ void att_mid_phase(
    float* sm, const float* Gp, const float* att_b,
    float* AH, const float* ACr, float* ACw,
    const float* query_W, const float* wcv, const float* wdv, const float* vvec,
    const float* pmT, const int* mlen,
    const float* AWr, const float* AWCr, float* E,
    const float* Gd, const float* dec_b, float* DH, float* DC, int step)
{
  float* ah_s = sm;          // 1024
  float* wd_s = sm+1024;     // 4096
  float* wc_s = sm+5120;     // 1984
  float* aw_s = sm+7104;     // 400
  float* awc_s= sm+7504;     // 400
  float* v_s  = sm+7904;     // 128
  float* q_s  = sm+8032;     // 128
  float* pool = sm+8160;     // 4608
  const int bid = blockIdx.x, tid = threadIdx.x;
  const int b = bid & 31, yD = bid >> 5;

  for (int i=tid;i<400;i+=NTHR){ aw_s[i]=ldf(AWr+b*400+i); awc_s[i]=ldf(AWCr+b*400+i); }
  for (int i=tid;i<4096;i+=NTHR) wd_s[i]=wdv[i];
  for (int i=tid;i<1984;i+=NTHR) wc_s[i]=wcv[i];
  if (tid<128) v_s[tid]=vvec[tid];

  // reduce att gate partials (8 slices), float2 sys loads
  for (int i=tid; i<2048; i+=NTHR){
    float2 s = {0,0};
    #pragma unroll
    for (int sl=0; sl<8; sl++){
      float2 v = ldf2(Gp + (size_t)sl*131072 + (size_t)b*4096 + i*2);
      s.x+=v.x; s.y+=v.y;
    }
    pool[i*2]=s.x; pool[i*2+1]=s.y;
  }
  __syncthreads();
  // att LSTM pointwise (redundant; yD==0 writes state)
  for (int u0=0; u0<2; u0++){
    int u = tid + u0*NTHR;
    float gi=pool[u]+att_b[u], gf=pool[1024+u]+att_b[1024+u];
    float gg=pool[2048+u]+att_b[2048+u], go=pool[3072+u]+att_b[3072+u];
    float c = sigm(gf)*ldf(ACr+b*1024+u) + sigm(gi)*ftanh(gg);
    float h = sigm(go)*ftanh(c);
    ah_s[u]=h;
    if (yD==0){ stf(ACw+b*1024+u, c); stf(AH+b*1024+u, h); }
  }
  __syncthreads();
  // q = ah @ query_W (4-way K split), qp in pool[0..512)
  { int a = tid & 127, sl = tid >> 7;
    float s=0.f; int kb = sl*256;
    for (int k=kb;k<kb+256;k++) s += ah_s[k]*query_W[k*128+a];
    pool[sl*128+a]=s; }
  __syncthreads();
  if (tid<128) q_s[tid] = pool[tid]+pool[128+tid]+pool[256+tid]+pool[384+tid];
  // distributed dec pointwise of step t-1 (units yD*128..+128)
  if (step>0 && tid<128){
    int u = yD*128 + tid;
    float gi=dec_b[u], gf=dec_b[1024+u], gg=dec_b[2048+u], go=dec_b[3072+u];
    #pragma unroll
    for (int sl=0; sl<8; sl++){
      const float* g = Gd + (size_t)sl*131072 + (size_t)b*4096;
      gi+=ldf(g+u); gf+=ldf(g+1024+u); gg+=ldf(g+2048+u); go+=ldf(g+3072+u);
    }
    float c = sigm(gf)*ldf(DC+b*1024+u) + sigm(gi)*ftanh(gg);
    float h = sigm(go)*ftanh(c);
    stf(DC+b*1024+u, c); stf(DH+b*1024+u, h);
  }
  __syncthreads();
  // conv location features for chunk (50 t)
  const int t0 = yD*50;
  float* loc = pool + 512;   // 50*33
  { int tl = tid & 63, fs = tid >> 6;
    if (tl < 50){
      float cf0=0,cf1=0,cf2=0,cf3=0;
      int f0 = fs*4;
      int tg = t0 + tl;
      for (int k=0;k<31;k++){
        int gi2 = tg + k - 15;
        float a1 = (gi2>=0 && gi2<400) ? aw_s[gi2] : 0.f;
        float a2 = (gi2>=0 && gi2<400) ? awc_s[gi2] : 0.f;
        cf0 += wc_s[(f0+0)*62+k]*a1 + wc_s[(f0+0)*62+31+k]*a2;
        cf1 += wc_s[(f0+1)*62+k]*a1 + wc_s[(f0+1)*62+31+k]*a2;
        cf2 += wc_s[(f0+2)*62+k]*a1 + wc_s[(f0+2)*62+31+k]*a2;
        cf3 += wc_s[(f0+3)*62+k]*a1 + wc_s[(f0+3)*62+31+k]*a2;
      }
      loc[tl*33+f0+0]=cf0; loc[tl*33+f0+1]=cf1;
      loc[tl*33+f0+2]=cf2; loc[tl*33+f0+3]=cf3;
    }
  }
  __syncthreads();
  // energies for chunk (pmT: read-only, cached, L2-resident per pinned block)
  float* ep = pool + 2176;   // 8*64
  { int tl = tid & 63, as = tid >> 6;
    if (tl < 50){
      int tg = t0 + tl;
      float e = 0.f;
      const float* lrow = loc + tl*33;
      for (int aa=0; aa<16; aa++){
        int a = as*16 + aa;
        float pmv = pmT[(size_t)b*51200 + (size_t)a*400 + tg];
        float lv = 0.f;
        #pragma unroll
        for (int f=0; f<32; f++) lv += lrow[f]*wd_s[f*128+a];
        e += ftanh(q_s[a]+pmv+lv)*v_s[a];
      }
      ep[as*64+tl] = e;
    }
  }
  __syncthreads();
  if (tid < 50){
    int tg = t0 + tid;
    float ee=0.f;
    #pragma unroll
    for (int as2=0; as2<8; as2++) ee += ep[as2*64+tid];
    stf(E+b*400+tg, (tg < mlen[b]) ? ee : -1e30f);
  }
}

// -------------------- phase C: softmax + ctx + proj(t-1) --------------------
__device__ __forceinline__ void softmax_ctx_phase(
    float* sm, const float* E, const float* memory,
    float* AWw, const float* AWCr, float* AWCw,
    float* CTXw, const float* CTXpp, const float* DH,
    const float* proj_W, const float* proj_b,
    const float* gate_W, const float* gate_b,
    float* out, float* aligns, int step)
{
  float* e_s = sm;           // 400
  float* red = sm+400;       // 16
  float* cp  = sm+416;       // 512
  float* do_s= sm+928;       // 1536
  float* pps = sm+2464;      // 486
  const int bid = blockIdx.x, tid = threadIdx.x;
  const int b = bid & 31, yD = bid >> 5;

  float ev = (tid<400) ? ldf(E+b*400+tid) : -1e30f;
  float m = ev;
  for (int off=32; off>0; off>>=1) m = fmaxf(m, __shfl_down(m, off, 64));
  if ((tid&63)==0) red[tid>>6]=m;
  __syncthreads();
  if (tid==0){ float mm=red[0]; for (int i=1;i<8;i++) mm=fmaxf(mm,red[i]); red[8]=mm; }
  __syncthreads();
  m = red[8];
  float ex = (tid<400) ? __expf(ev-m) : 0.f;
  float ss = ex;
  for (int off=32; off>0; off>>=1) ss += __shfl_down(ss, off, 64);
  if ((tid&63)==0) red[tid>>6]=ss;
  __syncthreads();
  if (tid==0){ float s2=0.f; for (int i=0;i<8;i++) s2+=red[i]; red[9]=1.f/s2; }
  __syncthreads();
  float anew = ex*red[9];
  if (tid<400) e_s[tid]=anew;
  if (yD==0 && tid<400){
    stf(AWw+b*400+tid, anew);
    stf(AWCw+b*400+tid, ldf(AWCr+b*400+tid) + anew);
    aligns[(size_t)b*160000 + (size_t)step*400 + tid] = anew;
  }
  __syncthreads();
  // ctx chunk (memory: read-only cached, L2-resident per pinned block)
  { int d = tid & 63, ts = tid >> 6;
    const int d0 = yD*64;
    const float* mrow = memory + (size_t)b*204800 + d0 + d;
    float pacc=0.f;
    for (int tt=ts*50; tt<ts*50+50; tt++) pacc += e_s[tt]*mrow[(size_t)tt*512];
    cp[ts*64+d]=pacc; }
  __syncthreads();
  if (tid<64){
    float s2=0.f;
    #pragma unroll
    for (int ts2=0; ts2<8; ts2++) s2+=cp[ts2*64+tid];
    stf(CTXw+b*512 + yD*64 + tid, s2);
  }
  // projections for step-1 (yD==0 only)
  if (yD==0 && step>0){
    for (int i=tid; i<1536; i+=NTHR)
      do_s[i] = (i<1024) ? ldf(DH+b*1024+i) : ldf(CTXpp+b*512 + (i-1024));
    __syncthreads();
    int sl = tid/81, o = tid - sl*81;
    if (sl < 6){
      float s=0.f; int kb = sl*256;
      for (int k=kb;k<kb+256;k++){
        float w2 = (o<80) ? proj_W[k*80+o] : gate_W[k];
        s += do_s[k]*w2;
      }
      pps[sl*81+o]=s;
    }
    __syncthreads();
    if (tid<81){
      float r=0.f;
      #pragma unroll
      for (int s2=0;s2<6;s2++) r += pps[s2*81+tid];
      if (tid<80) out[(size_t)b*32000 + tid*400 + (step-1)] = r + proj_b[tid];
      else        out[1024000 + b*400 + (step-1)] = r + gate_b[0];
    }
  }
}

// -------------------- epilogue: dec step 399 --------------------
__device__ __forceinline__ void dec_final_phase(
    float* sm, const float* Gd, const float* dec_b,
    const float* DC, const float* CTX1,
    const float* proj_W, const float* proj_b,
    const float* gate_W, const float* gate_b, float* out)
{
  float* g_s = sm;       // 4096
  float* do_s= sm+4096;  // 1536
  float* pps = sm+5632;  // 486
  const int b = blockIdx.x, tid = threadIdx.x;
  for (int i=tid; i<2048; i+=NTHR){
    float2 s = {0,0};
    #pragma unroll
    for (int sl=0; sl<8; sl++){
      float2 v = ldf2(Gd + (size_t)sl*131072 + (size_t)b*4096 + i*2);
      s.x+=v.x; s.y+=v.y;
    }
    g_s[i*2]=s.x; g_s[i*2+1]=s.y;
  }
  __syncthreads();
  for (int u0=0; u0<2; u0++){
    int u = tid + u0*NTHR;
    float gi=g_s[u]+dec_b[u], gf=g_s[1024+u]+dec_b[1024+u];
    float gg=g_s[2048+u]+dec_b[2048+u], go=g_s[3072+u]+dec_b[3072+u];
    float c = sigm(gf)*ldf(DC+b*1024+u) + sigm(gi)*ftanh(gg);
    do_s[u] = sigm(go)*ftanh(c);
  }
  do_s[1024+tid] = ldf(CTX1+b*512+tid);
  __syncthreads();
  int sl = tid/81, o = tid - sl*81;
  if (sl < 6){
    float s=0.f; int kb = sl*256;
    for (int k=kb;k<kb+256;k++){
      float w2 = (o<80) ? proj_W[k*80+o] : gate_W[k];
      s += do_s[k]*w2;
    }
    pps[sl*81+o]=s;
  }
  __syncthreads();
  if (tid<81){
    float r=0.f;
    #pragma unroll
    for (int s2=0;s2<6;s2++) r += pps[s2*81+tid];
    if (tid<80) out[(size_t)b*32000 + tid*400 + 399] = r + proj_b[tid];
    else        out[1024000 + b*400 + 399] = r + gate_b[0];
  }
}

// -------------------- the persistent cooperative kernel --------------------
__global__ void __launch_bounds__(NTHR) decoder_persist(
    const float* memory, const int* mlen, const float* query_W,
    const float* wcv, const float* wdv, const float* vvec,
    const float* att_Wih, const float* att_Whh, const float* att_b,
    const float* dec_Wih, const float* dec_Whh, const float* dec_b,
    const float* proj_W, const float* proj_b,
    const float* gate_W, const float* gate_b,
    float* ws, float* out)
{
  extern __shared__ float sm[];
  float* PRE  = ws + OFF_PRE;
  float* PMT  = ws + OFF_PMT;
  float* GATT = ws + OFF_GATT;
  float* GDEC = ws + OFF_GDEC;
  float* E    = ws + OFF_E;
  float* AH   = ws + OFF_AH;
  float* AC_[2] = { ws + OFF_AC0, ws + OFF_AC1 };
  float* DH   = ws + OFF_DH;
  float* DC   = ws + OFF_DC;
  float* AW_[2] = { ws + OFF_AW0, ws + OFF_AW1 };
  float* AWC_[2]= { ws + OFF_AWC0, ws + OFF_AWC1 };
  float* CTX_[2]= { ws + OFF_CTX0, ws + OFF_CTX1 };
  unsigned* bar = (unsigned*)(ws + OFF_BAR);
  float* aligns = out + 1036800;

  for (int t=0; t<400; t++){
    const int p = t & 1, pp = 1 - p;
    // A: att gates partials (K=1792 = 8 slices of 224)
    gates_phase<224,768>(sm, PRE + (size_t)t*8192, 256, CTX_[pp], 512, AH, 1024,
                         att_Wih, att_Whh, GATT);
    gsync(bar);
    // B: att reduce+pw+q+conv+energies + dec-pw(t-1)
    att_mid_phase(sm, GATT, att_b, AH, AC_[pp], AC_[p], query_W, wcv, wdv, vvec,
                  PMT, mlen, AW_[pp], AWC_[pp], E, GDEC, dec_b, DH, DC, t);
    gsync(bar);
    // C: softmax + ctx + proj(t-1)
    softmax_ctx_phase(sm, E, memory, AW_[p], AWC_[pp], AWC_[p], CTX_[p], CTX_[pp],
                      DH, proj_W, proj_b, gate_W, gate_b, out, aligns, t);
    gsync(bar);
    // D: dec gates partials (K=2560 = 8 slices of 320)
    gates_phase<320,1536>(sm, AH, 1024, CTX_[p], 512, DH, 1024,
                          dec_Wih, dec_Whh, GDEC);
    gsync(bar);
  }
  if (blockIdx.x < 32)
    dec_final_phase(sm, GDEC, dec_b, DC, CTX_[1], proj_W, proj_b, gate_W, gate_b, out);
}

// -------------------- launch --------------------

extern "C" void kernel_launch(void* const* d_in, const int* in_sizes, int n_in,
                              void* d_out, int out_size, void* d_ws, size_t ws_size,
                              hipStream_t stream) {
  const float* memory      = (const float*)d_in[0];
  const float* mel_target  = (const float*)d_in[1];
  const int*   mlen        = (const int*)  d_in[2];
  const float* prenet_W1   = (const float*)d_in[3];
  const float* prenet_W2   = (const float*)d_in[4];
  const float* query_W     = (const float*)d_in[5];
  const float* memory_W    = (const float*)d_in[6];
  const float* weight_vec  = (const float*)d_in[7];
  const float* loc_conv_W  = (const float*)d_in[8];
  const float* loc_dense_W = (const float*)d_in[9];
  const float* att_Wih     = (const float*)d_in[10];
  const float* att_Whh     = (const float*)d_in[11];
  const float* att_b       = (const float*)d_in[12];
  const float* dec_Wih     = (const float*)d_in[13];
  const float* dec_Whh     = (const float*)d_in[14];
  const float* dec_b       = (const float*)d_in[15];
  const float* proj_W      = (const float*)d_in[16];
  const float* proj_b      = (const float*)d_in[17];
  const float* gate_W      = (const float*)d_in[18];
  const float* gate_b      = (const float*)d_in[19];
  float* out = (float*)d_out;
  float* ws  = (float*)d_ws;

  float* PRE = ws + OFF_PRE;
  float* PMT = ws + OFF_PMT;

  // zero the entire used workspace every call -> replay-deterministic
  hipLaunchKernelGGL(zero_kernel, dim3((WS_TOTAL+255u)/256u), dim3(256), 0, stream, ws, WS_TOTAL);
  hipLaunchKernelGGL(prenet_kernel, dim3(12800), dim3(256), 0, stream,
                     mel_target, prenet_W1, prenet_W2, PRE);
  hipLaunchKernelGGL(pm_kernel, dim3(12800), dim3(128), 0, stream, memory, memory_W, PMT);

  void* args[] = {
    (void*)&memory, (void*)&mlen, (void*)&query_W,
    (void*)&loc_conv_W, (void*)&loc_dense_W, (void*)&weight_vec,
    (void*)&att_Wih, (void*)&att_Whh, (void*)&att_b,
    (void*)&dec_Wih, (void*)&dec_Whh, (void*)&dec_b,
    (void*)&proj_W, (void*)&proj_b, (void*)&gate_W, (void*)&gate_b,
    (void*)&ws, (void*)&out
  };
  hipLaunchCooperativeKernel((const void*)decoder_persist, dim3(NBLK), dim3(NTHR),
                             args, LDS_FLOATS*sizeof(float), stream);
}

// Round 10
// 117009.155 us; speedup vs baseline: 1.9174x; 1.1670x over previous
//
#include <hip/hip_runtime.h>

#define NBLK 256
#define NTHR 512

// ---------------- ws float offsets ----------------
#define OFF_PRE   0u            // [400][32][256]
#define OFF_PMT   3276800u      // [32][128][400]
#define OFF_GATT  4915200u      // [8][32][4096]
#define OFF_GDEC  5963776u      // [8][32][4096]
#define OFF_E     7012352u      // [32][400]
#define OFF_QP    7025152u      // [2][32][128]
#define OFF_AH    7033344u
#define OFF_AC0   7066112u
#define OFF_AC1   7098880u
#define OFF_DH    7131648u
#define OFF_DC    7164416u
#define OFF_AW0   7197184u
#define OFF_AW1   7209984u
#define OFF_AWC0  7222784u
#define OFF_AWC1  7235584u
#define OFF_CTX0  7248384u
#define OFF_CTX1  7264768u
#define OFF_BAR   7281152u
#define WS_TOTAL  7281168u      // 29.1 MB

#define LDS_FLOATS 13472        // xs 160*33 + wbuf 4*2048 = 53,888 B

__device__ __forceinline__ float sigm(float x){ return 1.f/(1.f+__expf(-x)); }
__device__ __forceinline__ float ftanh(float x){
  x = fminf(fmaxf(x,-15.f),15.f);
  float e = __expf(2.f*x);
  return (e-1.f)/(e+1.f);
}

typedef const __attribute__((address_space(1))) unsigned int* gas_t;
typedef __attribute__((address_space(3))) unsigned int* las_t;
typedef __attribute__((ext_vector_type(4))) float f32x4;

// UC scalar accessors (compile to global_load/store_dword sc0 sc1; HW-coalesced per wave)
__device__ __forceinline__ float ldf(const float* p){
  return __hip_atomic_load(p, __ATOMIC_RELAXED, __HIP_MEMORY_SCOPE_SYSTEM);
}
__device__ __forceinline__ void stf(float* p, float v){
  __hip_atomic_store(p, v, __ATOMIC_RELAXED, __HIP_MEMORY_SCOPE_SYSTEM);
}
// UC 16B store via asm (plain stores coalesce; atomics do not)
__device__ __forceinline__ void st_uc4(float* p, float4 v){
  f32x4 x = {v.x, v.y, v.z, v.w};
  asm volatile("global_store_dwordx4 %0, %1, off sc0 sc1" :: "v"(p), "v"(x) : "memory");
}

// fence-free grid barrier (R9-proven correct)
__device__ __forceinline__ void gsync(unsigned* bar){
  asm volatile("s_waitcnt vmcnt(0)" ::: "memory");
  __syncthreads();
  if (threadIdx.x==0){
    unsigned g = __hip_atomic_load(bar+1, __ATOMIC_RELAXED, __HIP_MEMORY_SCOPE_SYSTEM);
    unsigned arrived = __hip_atomic_fetch_add(bar, 1u, __ATOMIC_RELAXED, __HIP_MEMORY_SCOPE_SYSTEM);
    if (arrived == NBLK-1u){
      __hip_atomic_store(bar, 0u, __ATOMIC_RELAXED, __HIP_MEMORY_SCOPE_SYSTEM);
      asm volatile("s_waitcnt vmcnt(0)" ::: "memory");
      __hip_atomic_fetch_add(bar+1, 1u, __ATOMIC_RELAXED, __HIP_MEMORY_SCOPE_SYSTEM);
    } else {
      while (__hip_atomic_load(bar+1, __ATOMIC_RELAXED, __HIP_MEMORY_SCOPE_SYSTEM) == g){
        __builtin_amdgcn_s_sleep(8);
      }
    }
  }
  __syncthreads();
}

// -------------------- precompute --------------------

__global__ void zero_kernel(float* p, unsigned n){
  unsigned i = blockIdx.x*256u + threadIdx.x;
  if (i<n) p[i]=0.f;
}

__global__ __launch_bounds__(256) void prenet_kernel(const float* __restrict__ mel_target,
    const float* __restrict__ W1, const float* __restrict__ W2, float* __restrict__ pre)
{
  __shared__ float din[80];
  __shared__ float h1[256];
  int blk = blockIdx.x;          // t*32 + b
  int t = blk >> 5, b = blk & 31;
  int tid = threadIdx.x;
  if (tid < 80) din[tid] = (t==0) ? 0.f : mel_target[b*32000 + tid*400 + (t-1)];
  __syncthreads();
  float s=0.f;
  for (int c=0;c<80;c++) s += din[c]*W1[c*256+tid];
  h1[tid] = fmaxf(s,0.f);
  __syncthreads();
  float s2=0.f;
  for (int c=0;c<256;c++) s2 += h1[c]*W2[c*256+tid];
  pre[(size_t)blk*256 + tid] = fmaxf(s2,0.f);
}

__global__ __launch_bounds__(128) void pm_kernel(const float* __restrict__ memory,
    const float* __restrict__ memory_W, float* __restrict__ pmT)
{
  __shared__ float mrow[512];
  int blk = blockIdx.x;          // b*400 + t
  int b = blk/400, t = blk - b*400;
  int tid = threadIdx.x;
  const float* src = memory + (size_t)blk*512;
  for (int i=tid;i<512;i+=128) mrow[i]=src[i];
  __syncthreads();
  float s=0.f;
  for (int d=0; d<512; d++) s += mrow[d]*memory_W[d*128+tid];
  pmT[(size_t)b*51200 + tid*400 + t] = s;
}

// -------------------- W phase: one K-half of a gates GEMM --------------------
// 4-buffer global_load_lds pipeline, counted vmcnt (in-flight 3x8KB per CU).
template<int HSLICE, int KIH>
__device__ __forceinline__ void gates_half(float* xs, float* wbuf, int k_beg,
    const float* x0, int n0, const float* x1, int n1, const float* x2, int n2,
    const float* Wih, const float* Whh, int cb, float4& A0, float4& A1)
{
  constexpr int NT = HSLICE/16;
  const int tid = threadIdx.x;
  const int n01 = n0 + n1;
  __syncthreads();                    // previous users of xs/wbuf done
  for (int base=0; base<32*HSLICE; base+=NTHR){
    int idx = base + tid;
    if (idx < 32*HSLICE){
      int r = idx / HSLICE, kk = idx - r*HSLICE;
      int k = k_beg + kk;
      float v;
      if (k < n0) v = ldf(x0 + r*n0 + k);
      else if (k < n01) v = ldf(x1 + r*n1 + (k-n0));
      else v = ldf(x2 + r*n2 + (k-n01));
      xs[kk*33 + r] = v;
    }
  }
  __syncthreads();                    // drains vmcnt -> counted waits below are clean
  const int wv = tid>>6, lane = tid&63;
  const int fb = wv*1024 + lane*16;
  const int kk_l = fb >> 9;
  const int inner = fb & 511;
  const size_t colbB = (size_t)cb*512;
  auto STAGE = [&](int s){
    int k = k_beg + s*16 + kk_l;
    const char* row = (k < KIH) ? ((const char*)Wih + (size_t)k*16384)
                                : ((const char*)Whh + (size_t)(k-KIH)*16384);
    __builtin_amdgcn_global_load_lds((gas_t)(row + colbB + inner),
        (las_t)(wbuf + (s&3)*2048 + wv*256), 16, 0, 0);
  };
  STAGE(0); STAGE(1); STAGE(2);
  const int rg = tid>>5, cg = tid&31;
  const int r0 = rg*2;
  for (int s=0; s<NT; s++){
    int rem = NT-1-s;
    if (rem >= 2)      asm volatile("s_waitcnt vmcnt(2)" ::: "memory");
    else if (rem == 1) asm volatile("s_waitcnt vmcnt(1)" ::: "memory");
    else               asm volatile("s_waitcnt vmcnt(0)" ::: "memory");
    asm volatile("s_barrier" ::: "memory");
    const float* wb = wbuf + (s&3)*2048;
    const float* xk = xs + (s*16)*33;
    #pragma unroll
    for (int kk=0; kk<16; kk++){
      float4 w = *(const float4*)(wb + kk*128 + cg*4);
      float xv0 = xk[kk*33 + r0], xv1 = xk[kk*33 + r0 + 1];
      A0.x += xv0*w.x; A0.y += xv0*w.y; A0.z += xv0*w.z; A0.w += xv0*w.w;
      A1.x += xv1*w.x; A1.y += xv1*w.y; A1.z += xv1*w.z; A1.w += xv1*w.w;
    }
    if (s+3 < NT) STAGE(s+3);
  }
}

__device__ __forceinline__ void w_phase(float* sm,
    const float* pre_t, const float* CTXp, const float* AH, const float* DH,
    const float* att_Wih, const float* att_Whh, float* GATT,
    const float* dec_Wih, const float* dec_Whh, float* GDEC,
    bool do_att, bool do_dec)
{
  const int bid = blockIdx.x, tid = threadIdx.x;
  const int cb = bid & 31, kh = bid >> 5;
  float* xs = sm;             // 160*33 = 5280
  float* wbuf = sm + 5280;    // 4*2048
  const int rg = tid>>5, cg = tid&31, r0 = rg*2;
  if (do_att){
    float4 A0={0,0,0,0}, A1={0,0,0,0};
    int kb = kh*224;
    gates_half<112,768>(xs,wbuf,kb,     pre_t,256, CTXp,512, AH,1024, att_Wih,att_Whh, cb, A0,A1);
    gates_half<112,768>(xs,wbuf,kb+112, pre_t,256, CTXp,512, AH,1024, att_Wih,att_Whh, cb, A0,A1);
    float* gp = GATT + (size_t)kh*131072 + cb*128 + cg*4;
    st_uc4(gp + (size_t)(r0  )*4096, A0);
    st_uc4(gp + (size_t)(r0+1)*4096, A1);
    asm volatile("s_waitcnt vmcnt(0)" ::: "memory");  // drain stores before counted waits
  }
  if (do_dec){
    float4 A0={0,0,0,0}, A1={0,0,0,0};
    int kb = kh*320;
    gates_half<160,1536>(xs,wbuf,kb,     AH,1024, CTXp,512, DH,1024, dec_Wih,dec_Whh, cb, A0,A1);
    gates_half<160,1536>(xs,wbuf,kb+160, AH,1024, CTXp,512, DH,1024, dec_Wih,dec_Whh, cb, A0,A1);
    float* gp = GDEC + (size_t)kh*131072 + cb*128 + cg*4;
    st_uc4(gp + (size_t)(r0  )*4096, A0);
    st_uc4(gp + (size_t)(r0+1)*4096, A1);
  }
}

// -------------------- B1: reduce + LSTM pointwise + q halves --------------------
// roles: 0/1 att half-units; 2/3 dec half-units (step t-1); 4-7 idle
__device__ __forceinline__ void b1_phase(float* sm,
    const float* GATT, const float* GDEC,
    const float* att_b, const float* dec_b, const float* query_W,
    float* AH, const float* ACr, float* ACw, float* DH, float* DC,
    float* QP, int step)
{
  const int bid = blockIdx.x, tid = threadIdx.x;
  const int b = bid & 31, role = bid >> 5;
  if (role < 2){
    float* ah_s = sm;          // 512
    float* pool = sm + 512;    // 512
    const int h = role;
    const int u = h*512 + tid;
    float g4[4];
    #pragma unroll
    for (int g=0; g<4; g++){
      float s = att_b[g*1024 + u];
      #pragma unroll
      for (int sl=0; sl<8; sl++)
        s += ldf(GATT + (size_t)sl*131072 + (size_t)b*4096 + g*1024 + u);
      g4[g] = s;
    }
    float c = sigm(g4[1])*ldf(ACr + b*1024 + u) + sigm(g4[0])*ftanh(g4[2]);
    float hv = sigm(g4[3])*ftanh(c);
    stf(ACw + b*1024 + u, c);
    stf(AH  + b*1024 + u, hv);
    ah_s[tid] = hv;
    __syncthreads();
    { int a = tid & 127, sl = tid >> 7;
      float s = 0.f; int kb = sl*128;
      for (int k=kb; k<kb+128; k++) s += ah_s[k]*query_W[(h*512+k)*128 + a];
      pool[sl*128+a] = s; }
    __syncthreads();
    if (tid < 128)
      stf(QP + h*4096 + b*128 + tid,
          pool[tid]+pool[128+tid]+pool[256+tid]+pool[384+tid]);
  } else if (role < 4 && step > 0){
    const int h = role - 2;
    const int u = h*512 + tid;
    float g4[4];
    #pragma unroll
    for (int g=0; g<4; g++){
      float s = dec_b[g*1024 + u];
      #pragma unroll
      for (int sl=0; sl<8; sl++)
        s += ldf(GDEC + (size_t)sl*131072 + (size_t)b*4096 + g*1024 + u);
      g4[g] = s;
    }
    float c = sigm(g4[1])*ldf(DC + b*1024 + u) + sigm(g4[0])*ftanh(g4[2]);
    float hv = sigm(g4[3])*ftanh(c);
    stf(DC + b*1024 + u, c);
    stf(DH + b*1024 + u, hv);
  }
}

// -------------------- B2: conv + energies (b=bid&31, chunk yD of 50 t) --------------------
__device__ __forceinline__ void b2_phase(float* sm,
    const float* wcv, const float* wdv, const float* vvec,
    const float* pmT, const int* mlen,
    const float* AWr, const float* AWCr, const float* QP, float* E)
{
  float* aw_s = sm;         // 400
  float* awc_s= sm+400;     // 400
  float* wc_s = sm+800;     // 1984
  float* wd_s = sm+2784;    // 4096
  float* v_s  = sm+6880;    // 128
  float* q_s  = sm+7008;    // 128
  float* loc  = sm+7136;    // 50*33 = 1650
  float* ep   = sm+8800;    // 8*64
  const int bid = blockIdx.x, tid = threadIdx.x;
  const int b = bid & 31, yD = bid >> 5;
  for (int i=tid;i<400;i+=NTHR){ aw_s[i]=ldf(AWr+b*400+i); awc_s[i]=ldf(AWCr+b*400+i); }
  for (int i=tid;i<4096;i+=NTHR) wd_s[i]=wdv[i];
  for (int i=tid;i<1984;i+=NTHR) wc_s[i]=wcv[i];
  if (tid<128){
    v_s[tid]=vvec[tid];
    q_s[tid] = ldf(QP + b*128 + tid) + ldf(QP + 4096 + b*128 + tid);
  }
  __syncthreads();
  const int t0 = yD*50;
  { int tl = tid & 63, fs = tid >> 6;
    if (tl < 50){
      float cf0=0,cf1=0,cf2=0,cf3=0;
      int f0 = fs*4;
      int tg = t0 + tl;
      for (int k=0;k<31;k++){
        int gi2 = tg + k - 15;
        float a1 = (gi2>=0 && gi2<400) ? aw_s[gi2] : 0.f;
        float a2 = (gi2>=0 && gi2<400) ? awc_s[gi2] : 0.f;
        cf0 += wc_s[(f0+0)*62+k]*a1 + wc_s[(f0+0)*62+31+k]*a2;
        cf1 += wc_s[(f0+1)*62+k]*a1 + wc_s[(f0+1)*62+31+k]*a2;
        cf2 += wc_s[(f0+2)*62+k]*a1 + wc_s[(f0+2)*62+31+k]*a2;
        cf3 += wc_s[(f0+3)*62+k]*a1 + wc_s[(f0+3)*62+31+k]*a2;
      }
      loc[tl*33+f0+0]=cf0; loc[tl*33+f0+1]=cf1;
      loc[tl*33+f0+2]=cf2; loc[tl*33+f0+3]=cf3;
    }
  }
  __syncthreads();
  { int tl = tid & 63, as = tid >> 6;
    if (tl < 50){
      int tg = t0 + tl;
      float e = 0.f;
      const float* lrow = loc + tl*33;
      for (int aa=0; aa<16; aa++){
        int a = as*16 + aa;
        float pmv = pmT[(size_t)b*51200 + (size_t)a*400 + tg];
        float lv = 0.f;
        #pragma unroll
        for (int f=0; f<32; f++) lv += lrow[f]*wd_s[f*128+a];
        e += ftanh(q_s[a]+pmv+lv)*v_s[a];
      }
      ep[as*64+tl] = e;
    }
  }
  __syncthreads();
  if (tid < 50){
    int tg = t0 + tid;
    float ee=0.f;
    #pragma unroll
    for (int as2=0; as2<8; as2++) ee += ep[as2*64+tid];
    stf(E + b*400 + tg, (tg < mlen[b]) ? ee : -1e30f);
  }
}

// -------------------- C: softmax + ctx + proj(t-1) --------------------
__device__ __forceinline__ void c_phase(float* sm, const float* E, const float* memory,
    float* AWw, const float* AWCr, float* AWCw,
    float* CTXw, const float* CTXpp, const float* DH,
    const float* proj_W, const float* proj_b,
    const float* gate_W, const float* gate_b,
    float* out, float* aligns, int step)
{
  float* e_s = sm;           // 400
  float* red = sm+400;       // 16
  float* cp  = sm+416;       // 512
  float* do_s= sm+928;       // 1536
  float* pps = sm+2464;      // 486
  const int bid = blockIdx.x, tid = threadIdx.x;
  const int b = bid & 31, yD = bid >> 5;

  float ev = (tid<400) ? ldf(E+b*400+tid) : -1e30f;
  float m = ev;
  for (int off=32; off>0; off>>=1) m = fmaxf(m, __shfl_down(m, off, 64));
  if ((tid&63)==0) red[tid>>6]=m;
  __syncthreads();
  if (tid==0){ float mm=red[0]; for (int i=1;i<8;i++) mm=fmaxf(mm,red[i]); red[8]=mm; }
  __syncthreads();
  m = red[8];
  float ex = (tid<400) ? __expf(ev-m) : 0.f;
  float ss = ex;
  for (int off=32; off>0; off>>=1) ss += __shfl_down(ss, off, 64);
  if ((tid&63)==0) red[tid>>6]=ss;
  __syncthreads();
  if (tid==0){ float s2=0.f; for (int i=0;i<8;i++) s2+=red[i]; red[9]=1.f/s2; }
  __syncthreads();
  float anew = ex*red[9];
  if (tid<400) e_s[tid]=anew;
  if (yD==0 && tid<400){
    stf(AWw+b*400+tid, anew);
    stf(AWCw+b*400+tid, ldf(AWCr+b*400+tid) + anew);
    aligns[(size_t)b*160000 + (size_t)step*400 + tid] = anew;
  }
  __syncthreads();
  { int d = tid & 63, ts = tid >> 6;
    const int d0 = yD*64;
    const float* mrow = memory + (size_t)b*204800 + d0 + d;
    float pacc=0.f;
    for (int tt=ts*50; tt<ts*50+50; tt++) pacc += e_s[tt]*mrow[(size_t)tt*512];
    cp[ts*64+d]=pacc; }
  __syncthreads();
  if (tid<64){
    float s2=0.f;
    #pragma unroll
    for (int ts2=0; ts2<8; ts2++) s2+=cp[ts2*64+tid];
    stf(CTXw + b*512 + yD*64 + tid, s2);
  }
  if (yD==0 && step>0){
    for (int i=tid; i<1536; i+=NTHR)
      do_s[i] = (i<1024) ? ldf(DH+b*1024+i) : ldf(CTXpp+b*512 + (i-1024));
    __syncthreads();
    int sl = tid/81, o = tid - sl*81;
    if (sl < 6){
      float s=0.f; int kb = sl*256;
      for (int k=kb;k<kb+256;k++){
        float w2 = (o<80) ? proj_W[k*80+o] : gate_W[k];
        s += do_s[k]*w2;
      }
      pps[sl*81+o]=s;
    }
    __syncthreads();
    if (tid<81){
      float r=0.f;
      #pragma unroll
      for (int s2=0;s2<6;s2++) r += pps[s2*81+tid];
      if (tid<80) out[(size_t)b*32000 + tid*400 + (step-1)] = r + proj_b[tid];
      else        out[1024000 + b*400 + (step-1)] = r + gate_b[0];
    }
  }
}

// -------------------- epilogue: dec step 399 --------------------
__device__ __forceinline__ void dec_final_phase(float* sm,
    const float* Gd, const float* dec_b,
    const float* DC, const float* CTX1,
    const float* proj_W, const float* proj_b,
    const float* gate_W, const float* gate_b, float* out)
{
  float* do_s = sm;       // 1536
  float* pps  = sm+1536;  // 486
  const int b = blockIdx.x, tid = threadIdx.x;
  for (int u0=0; u0<2; u0++){
    int u = tid + u0*512;
    float g4[4];
    #pragma unroll
    for (int g=0; g<4; g++){
      float s = dec_b[g*1024 + u];
      #pragma unroll
      for (int sl=0; sl<8; sl++)
        s += ldf(Gd + (size_t)sl*131072 + (size_t)b*4096 + g*1024 + u);
      g4[g] = s;
    }
    float c = sigm(g4[1])*ldf(DC + b*1024 + u) + sigm(g4[0])*ftanh(g4[2]);
    do_s[u] = sigm(g4[3])*ftanh(c);
  }
  do_s[1024+tid] = ldf(CTX1 + b*512 + tid);
  __syncthreads();
  int sl = tid/81, o = tid - sl*81;
  if (sl < 6){
    float s=0.f; int kb = sl*256;
    for (int k=kb;k<kb+256;k++){
      float w2 = (o<80) ? proj_W[k*80+o] : gate_W[k];
      s += do_s[k]*w2;
    }
    pps[sl*81+o]=s;
  }
  __syncthreads();
  if (tid<81){
    float r=0.f;
    #pragma unroll
    for (int s2=0;s2<6;s2++) r += pps[s2*81+tid];
    if (tid<80) out[(size_t)b*32000 + tid*400 + 399] = r + proj_b[tid];
    else        out[1024000 + b*400 + 399] = r + gate_b[0];
  }
}

// -------------------- persistent cooperative kernel --------------------
__global__ void __launch_bounds__(NTHR) decoder_persist(
    const float* memory, const int* mlen, const float* query_W,
    const float* wcv, const float* wdv, const float* vvec,
    const float* att_Wih, const float* att_Whh, const float* att_b,
    const float* dec_Wih, const float* dec_Whh, const float* dec_b,
    const float* proj_W, const float* proj_b,
    const float* gate_W, const float* gate_b,
    float* ws, float* out)
{
  extern __shared__ float sm[];
  float* PRE  = ws + OFF_PRE;
  float* PMT  = ws + OFF_PMT;
  float* GATT = ws + OFF_GATT;
  float* GDEC = ws + OFF_GDEC;
  float* E    = ws + OFF_E;
  float* QP   = ws + OFF_QP;
  float* AH   = ws + OFF_AH;
  float* AC_[2] = { ws + OFF_AC0, ws + OFF_AC1 };
  float* DH   = ws + OFF_DH;
  float* DC   = ws + OFF_DC;
  float* AW_[2] = { ws + OFF_AW0, ws + OFF_AW1 };
  float* AWC_[2]= { ws + OFF_AWC0, ws + OFF_AWC1 };
  float* CTX_[2]= { ws + OFF_CTX0, ws + OFF_CTX1 };
  unsigned* bar = (unsigned*)(ws + OFF_BAR);
  float* aligns = out + 1036800;

  // prologue: GATT(0) from zero state
  w_phase(sm, PRE, CTX_[1], AH, DH, att_Wih, att_Whh, GATT,
          dec_Wih, dec_Whh, GDEC, true, false);
  gsync(bar);

  for (int t=0; t<400; t++){
    const int p = t & 1, pp = 1 - p;
    // B1: att reduce+pw+q halves; dec pw of t-1
    b1_phase(sm, GATT, GDEC, att_b, dec_b, query_W,
             AH, AC_[pp], AC_[p], DH, DC, QP, t);
    gsync(bar);
    // B2: conv + energies
    b2_phase(sm, wcv, wdv, vvec, PMT, mlen, AW_[pp], AWC_[pp], QP, E);
    gsync(bar);
    // C: softmax + ctx + proj(t-1)
    c_phase(sm, E, memory, AW_[p], AWC_[pp], AWC_[p], CTX_[p], CTX_[pp],
            DH, proj_W, proj_b, gate_W, gate_b, out, aligns, t);
    gsync(bar);
    // W: GATT(t+1) [skip at 399] + GDEC(t)
    w_phase(sm, (t<399) ? (PRE + (size_t)(t+1)*8192) : PRE, CTX_[p], AH, DH,
            att_Wih, att_Whh, GATT, dec_Wih, dec_Whh, GDEC, t<399, true);
    gsync(bar);
  }
  if (blockIdx.x < 32)
    dec_final_phase(sm, GDEC, dec_b, DC, CTX_[1],
                    proj_W, proj_b, gate_W, gate_b, out);
}

// -------------------- launch --------------------

extern "C" void kernel_launch(void* const* d_in, const int* in_sizes, int n_in,
                              void* d_out, int out_size, void* d_ws, size_t ws_size,
                              hipStream_t stream) {
  const float* memory      = (const float*)d_in[0];
  const float* mel_target  = (const float*)d_in[1];
  const int*   mlen        = (const int*)  d_in[2];
  const float* prenet_W1   = (const float*)d_in[3];
  const float* prenet_W2   = (const float*)d_in[4];
  const float* query_W     = (const float*)d_in[5];
  const float* memory_W    = (const float*)d_in[6];
  const float* weight_vec  = (const float*)d_in[7];
  const float* loc_conv_W  = (const float*)d_in[8];
  const float* loc_dense_W = (const float*)d_in[9];
  const float* att_Wih     = (const float*)d_in[10];
  const float* att_Whh     = (const float*)d_in[11];
  const float* att_b       = (const float*)d_in[12];
  const float* dec_Wih     = (const float*)d_in[13];
  const float* dec_Whh     = (const float*)d_in[14];
  const float* dec_b       = (const float*)d_in[15];
  const float* proj_W      = (const float*)d_in[16];
  const float* proj_b      = (const float*)d_in[17];
  const float* gate_W      = (const float*)d_in[18];
  const float* gate_b      = (const float*)d_in[19];
  float* out = (float*)d_out;
  float* ws  = (float*)d_ws;

  float* PRE = ws + OFF_PRE;
  float* PMT = ws + OFF_PMT;

  // zero the entire used workspace every call -> replay-deterministic
  hipLaunchKernelGGL(zero_kernel, dim3((WS_TOTAL+255u)/256u), dim3(256), 0, stream, ws, WS_TOTAL);
  hipLaunchKernelGGL(prenet_kernel, dim3(12800), dim3(256), 0, stream,
                     mel_target, prenet_W1, prenet_W2, PRE);
  hipLaunchKernelGGL(pm_kernel, dim3(12800), dim3(128), 0, stream, memory, memory_W, PMT);

  void* args[] = {
    (void*)&memory, (void*)&mlen, (void*)&query_W,
    (void*)&loc_conv_W, (void*)&loc_dense_W, (void*)&weight_vec,
    (void*)&att_Wih, (void*)&att_Whh, (void*)&att_b,
    (void*)&dec_Wih, (void*)&dec_Whh, (void*)&dec_b,
    (void*)&proj_W, (void*)&proj_b, (void*)&gate_W, (void*)&gate_b,
    (void*)&ws, (void*)&out
  };
  hipLaunchCooperativeKernel((const void*)decoder_persist, dim3(NBLK), dim3(NTHR),
                             args, LDS_FLOATS*sizeof(float), stream);
}

// Round 12
// 102563.586 us; speedup vs baseline: 2.1874x; 1.1408x over previous
//
#include <hip/hip_runtime.h>

#define NBLK 256
#define NTHR 512

// ---------------- ws float offsets ----------------
#define OFF_PRE   0u            // [400][32][256]
#define OFF_PMT   3276800u      // [32][128][400]
#define OFF_GATT  4915200u      // [8][32][4096]
#define OFF_GDEC  5963776u      // [8][32][4096]
#define OFF_E     7012352u      // [32][400]
#define OFF_QP    7025152u      // [2][32][128]
#define OFF_AH    7033344u
#define OFF_AC0   7066112u
#define OFF_AC1   7098880u
#define OFF_DH    7131648u
#define OFF_DC    7164416u
#define OFF_AW0   7197184u
#define OFF_AW1   7209984u
#define OFF_AWC0  7222784u
#define OFF_AWC1  7235584u
#define OFF_CTX0  7248384u
#define OFF_CTX1  7264768u
#define OFF_BAR   7281152u      // hierarchical barrier lines (512 uints)
#define WS_TOTAL  7281664u      // 29.1 MB

#define LDS_FLOATS 13472        // xs 160*33 + wbuf 4*2048 = 53,888 B

__device__ __forceinline__ float sigm(float x){ return 1.f/(1.f+__expf(-x)); }
__device__ __forceinline__ float ftanh(float x){
  x = fminf(fmaxf(x,-15.f),15.f);
  float e = __expf(2.f*x);
  return (e-1.f)/(e+1.f);
}

typedef const __attribute__((address_space(1))) unsigned int* gas_t;
typedef __attribute__((address_space(3))) unsigned int* las_t;
typedef __attribute__((ext_vector_type(4))) float f32x4;

__device__ __forceinline__ float ldf(const float* p){
  return __hip_atomic_load(p, __ATOMIC_RELAXED, __HIP_MEMORY_SCOPE_SYSTEM);
}
__device__ __forceinline__ void stf(float* p, float v){
  __hip_atomic_store(p, v, __ATOMIC_RELAXED, __HIP_MEMORY_SCOPE_SYSTEM);
}
__device__ __forceinline__ void st_uc4(float* p, float4 v){
  f32x4 x = {v.x, v.y, v.z, v.w};
  asm volatile("global_store_dwordx4 %0, %1, off sc0 sc1" :: "v"(p), "v"(x) : "memory");
}
__device__ __forceinline__ unsigned uld(unsigned* p){
  return __hip_atomic_load(p, __ATOMIC_RELAXED, __HIP_MEMORY_SCOPE_SYSTEM);
}
__device__ __forceinline__ void ust(unsigned* p, unsigned v){
  __hip_atomic_store(p, v, __ATOMIC_RELAXED, __HIP_MEMORY_SCOPE_SYSTEM);
}
__device__ __forceinline__ unsigned ufadd(unsigned* p){
  return __hip_atomic_fetch_add(p, 1u, __ATOMIC_RELAXED, __HIP_MEMORY_SCOPE_SYSTEM);
}

// two-level fence-free grid barrier: 8 groups (bid&7 ~ XCD) on padded lines,
// group masters rendezvous on one line. Same vmcnt discipline as R9/R10.
__device__ __forceinline__ void gsync(unsigned* bb){
  asm volatile("s_waitcnt vmcnt(0)" ::: "memory");
  __syncthreads();
  if (threadIdx.x==0){
    const int g = blockIdx.x & 7;
    unsigned* gcnt = bb + g*32;
    unsigned* ggen = bb + g*32 + 16;
    unsigned* mcnt = bb + 256;
    unsigned* mgen = bb + 256 + 16;
    unsigned gg = uld(ggen);
    unsigned arr = ufadd(gcnt);
    if (arr == 31u){
      unsigned mg = uld(mgen);
      unsigned ma = ufadd(mcnt);
      if (ma == 7u){
        ust(mcnt, 0u);
        asm volatile("s_waitcnt vmcnt(0)" ::: "memory");
        ufadd(mgen);
      } else {
        while (uld(mgen) == mg){ __builtin_amdgcn_s_sleep(2); }
      }
      ust(gcnt, 0u);
      asm volatile("s_waitcnt vmcnt(0)" ::: "memory");
      ufadd(ggen);
    } else {
      while (uld(ggen) == gg){ __builtin_amdgcn_s_sleep(2); }
    }
  }
  __syncthreads();
}

// -------------------- precompute --------------------

__global__ void zero_kernel(float* p, unsigned n){
  unsigned i = blockIdx.x*256u + threadIdx.x;
  if (i<n) p[i]=0.f;
}

__global__ __launch_bounds__(256) void prenet_kernel(const float* __restrict__ mel_target,
    const float* __restrict__ W1, const float* __restrict__ W2, float* __restrict__ pre)
{
  __shared__ float din[80];
  __shared__ float h1[256];
  int blk = blockIdx.x;          // t*32 + b
  int t = blk >> 5, b = blk & 31;
  int tid = threadIdx.x;
  if (tid < 80) din[tid] = (t==0) ? 0.f : mel_target[b*32000 + tid*400 + (t-1)];
  __syncthreads();
  float s=0.f;
  for (int c=0;c<80;c++) s += din[c]*W1[c*256+tid];
  h1[tid] = fmaxf(s,0.f);
  __syncthreads();
  float s2=0.f;
  for (int c=0;c<256;c++) s2 += h1[c]*W2[c*256+tid];
  pre[(size_t)blk*256 + tid] = fmaxf(s2,0.f);
}

__global__ __launch_bounds__(128) void pm_kernel(const float* __restrict__ memory,
    const float* __restrict__ memory_W, float* __restrict__ pmT)
{
  __shared__ float mrow[512];
  int blk = blockIdx.x;          // b*400 + t
  int b = blk/400, t = blk - b*400;
  int tid = threadIdx.x;
  const float* src = memory + (size_t)blk*512;
  for (int i=tid;i<512;i+=128) mrow[i]=src[i];
  __syncthreads();
  float s=0.f;
  for (int d=0; d<512; d++) s += mrow[d]*memory_W[d*128+tid];
  pmT[(size_t)b*51200 + tid*400 + t] = s;
}

// -------------------- W phase: one K-half of a gates GEMM --------------------
// 4-buffer global_load_lds pipeline, counted vmcnt; weight loads NT|SC1 (aux=0x12)
// to stream via the HBM path without L2/L3 allocation contention.
template<int HSLICE, int KIH>
__device__ __forceinline__ void gates_half(float* xs, float* wbuf, int k_beg,
    const float* x0, int n0, const float* x1, int n1, const float* x2, int n2,
    const float* Wih, const float* Whh, int cb, float4& A0, float4& A1)
{
  constexpr int NT = HSLICE/16;
  const int tid = threadIdx.x;
  const int n01 = n0 + n1;
  __syncthreads();                    // previous users of xs/wbuf done
  for (int base=0; base<32*HSLICE; base+=NTHR){
    int idx = base + tid;
    if (idx < 32*HSLICE){
      int r = idx / HSLICE, kk = idx - r*HSLICE;
      int k = k_beg + kk;
      float v;
      if (k < n0) v = ldf(x0 + r*n0 + k);
      else if (k < n01) v = ldf(x1 + r*n1 + (k-n0));
      else v = ldf(x2 + r*n2 + (k-n01));
      xs[kk*33 + r] = v;
    }
  }
  __syncthreads();                    // drains vmcnt -> counted waits below are clean
  const int wv = tid>>6, lane = tid&63;
  const int fb = wv*1024 + lane*16;
  const int kk_l = fb >> 9;
  const int inner = fb & 511;
  const size_t colbB = (size_t)cb*512;
  auto STAGE = [&](int s){
    int k = k_beg + s*16 + kk_l;
    const char* row = (k < KIH) ? ((const char*)Wih + (size_t)k*16384)
                                : ((const char*)Whh + (size_t)(k-KIH)*16384);
    __builtin_amdgcn_global_load_lds((gas_t)(row + colbB + inner),
        (las_t)(wbuf + (s&3)*2048 + wv*256), 16, 0, 0x12 /*NT|SC1*/);
  };
  STAGE(0); STAGE(1); STAGE(2);
  const int rg = tid>>5, cg = tid&31;
  const int r0 = rg*2;
  for (int s=0; s<NT; s++){
    int rem = NT-1-s;
    if (rem >= 2)      asm volatile("s_waitcnt vmcnt(2)" ::: "memory");
    else if (rem == 1) asm volatile("s_waitcnt vmcnt(1)" ::: "memory");
    else               asm volatile("s_waitcnt vmcnt(0)" ::: "memory");
    asm volatile("s_barrier" ::: "memory");
    const float* wb = wbuf + (s&3)*2048;
    const float* xk = xs + (s*16)*33;
    #pragma unroll
    for (int kk=0; kk<16; kk++){
      float4 w = *(const float4*)(wb + kk*128 + cg*4);
      float xv0 = xk[kk*33 + r0], xv1 = xk[kk*33 + r0 + 1];
      A0.x += xv0*w.x; A0.y += xv0*w.y; A0.z += xv0*w.z; A0.w += xv0*w.w;
      A1.x += xv1*w.x; A1.y += xv1*w.y; A1.z += xv1*w.z; A1.w += xv1*w.w;
    }
    if (s+3 < NT) STAGE(s+3);
  }
}

__device__ __forceinline__ void w_phase(float* sm,
    const float* pre_t, const float* CTXp, const float* AH, const float* DH,
    const float* att_Wih, const float* att_Whh, float* GATT,
    const float* dec_Wih, const float* dec_Whh, float* GDEC,
    bool do_att, bool do_dec)
{
  const int bid = blockIdx.x, tid = threadIdx.x;
  const int cb = bid & 31, kh = bid >> 5;
  float* xs = sm;             // 160*33 = 5280
  float* wbuf = sm + 5280;    // 4*2048
  const int rg = tid>>5, cg = tid&31, r0 = rg*2;
  if (do_att){
    float4 A0={0,0,0,0}, A1={0,0,0,0};
    int kb = kh*224;
    gates_half<112,768>(xs,wbuf,kb,     pre_t,256, CTXp,512, AH,1024, att_Wih,att_Whh, cb, A0,A1);
    gates_half<112,768>(xs,wbuf,kb+112, pre_t,256, CTXp,512, AH,1024, att_Wih,att_Whh, cb, A0,A1);
    float* gp = GATT + (size_t)kh*131072 + cb*128 + cg*4;
    st_uc4(gp + (size_t)(r0  )*4096, A0);
    st_uc4(gp + (size_t)(r0+1)*4096, A1);
    asm volatile("s_waitcnt vmcnt(0)" ::: "memory");  // drain stores before counted waits
  }
  if (do_dec){
    float4 A0={0,0,0,0}, A1={0,0,0,0};
    int kb = kh*320;
    gates_half<160,1536>(xs,wbuf,kb,     AH,1024, CTXp,512, DH,1024, dec_Wih,dec_Whh, cb, A0,A1);
    gates_half<160,1536>(xs,wbuf,kb+160, AH,1024, CTXp,512, DH,1024, dec_Wih,dec_Whh, cb, A0,A1);
    float* gp = GDEC + (size_t)kh*131072 + cb*128 + cg*4;
    st_uc4(gp + (size_t)(r0  )*4096, A0);
    st_uc4(gp + (size_t)(r0+1)*4096, A1);
  }
}

// -------------------- B1: reduce + LSTM pointwise + q halves --------------------
__device__ __forceinline__ void b1_phase(float* sm,
    const float* GATT, const float* GDEC,
    const float* att_b, const float* dec_b, const float* query_W,
    float* AH, const float* ACr, float* ACw, float* DH, float* DC,
    float* QP, int step)
{
  const int bid = blockIdx.x, tid = threadIdx.x;
  const int b = bid & 31, role = bid >> 5;
  if (role < 2){
    float* ah_s = sm;          // 512
    float* pool = sm + 512;    // 512
    const int h = role;
    const int u = h*512 + tid;
    float g4[4];
    #pragma unroll
    for (int g=0; g<4; g++){
      float s = att_b[g*1024 + u];
      #pragma unroll
      for (int sl=0; sl<8; sl++)
        s += ldf(GATT + (size_t)sl*131072 + (size_t)b*4096 + g*1024 + u);
      g4[g] = s;
    }
    float c = sigm(g4[1])*ldf(ACr + b*1024 + u) + sigm(g4[0])*ftanh(g4[2]);
    float hv = sigm(g4[3])*ftanh(c);
    stf(ACw + b*1024 + u, c);
    stf(AH  + b*1024 + u, hv);
    ah_s[tid] = hv;
    __syncthreads();
    { int a = tid & 127, sl = tid >> 7;
      float s = 0.f; int kb = sl*128;
      for (int k=kb; k<kb+128; k++) s += ah_s[k]*query_W[(h*512+k)*128 + a];
      pool[sl*128+a] = s; }
    __syncthreads();
    if (tid < 128)
      stf(QP + h*4096 + b*128 + tid,
          pool[tid]+pool[128+tid]+pool[256+tid]+pool[384+tid]);
  } else if (role < 4 && step > 0){
    const int h = role - 2;
    const int u = h*512 + tid;
    float g4[4];
    #pragma unroll
    for (int g=0; g<4; g++){
      float s = dec_b[g*1024 + u];
      #pragma unroll
      for (int sl=0; sl<8; sl++)
        s += ldf(GDEC + (size_t)sl*131072 + (size_t)b*4096 + g*1024 + u);
      g4[g] = s;
    }
    float c = sigm(g4[1])*ldf(DC + b*1024 + u) + sigm(g4[0])*ftanh(g4[2]);
    float hv = sigm(g4[3])*ftanh(c);
    stf(DC + b*1024 + u, c);
    stf(DH + b*1024 + u, hv);
  }
}

// -------------------- B2: conv + energies (b=bid&31, chunk yD of 50 t) --------------------
__device__ __forceinline__ void b2_phase(float* sm,
    const float* wcv, const float* wdv, const float* vvec,
    const float* pmT, const int* mlen,
    const float* AWr, const float* AWCr, const float* QP, float* E)
{
  float* aw_s = sm;         // 400
  float* awc_s= sm+400;     // 400
  float* wc_s = sm+800;     // 1984
  float* wd_s = sm+2784;    // 4096
  float* v_s  = sm+6880;    // 128
  float* q_s  = sm+7008;    // 128
  float* loc  = sm+7136;    // 50*33 = 1650
  float* ep   = sm+8800;    // 8*64
  const int bid = blockIdx.x, tid = threadIdx.x;
  const int b = bid & 31, yD = bid >> 5;
  for (int i=tid;i<400;i+=NTHR){ aw_s[i]=ldf(AWr+b*400+i); awc_s[i]=ldf(AWCr+b*400+i); }
  for (int i=tid;i<4096;i+=NTHR) wd_s[i]=wdv[i];
  for (int i=tid;i<1984;i+=NTHR) wc_s[i]=wcv[i];
  if (tid<128){
    v_s[tid]=vvec[tid];
    q_s[tid] = ldf(QP + b*128 + tid) + ldf(QP + 4096 + b*128 + tid);
  }
  __syncthreads();
  const int t0 = yD*50;
  { int tl = tid & 63, fs = tid >> 6;
    if (tl < 50){
      float cf0=0,cf1=0,cf2=0,cf3=0;
      int f0 = fs*4;
      int tg = t0 + tl;
      for (int k=0;k<31;k++){
        int gi2 = tg + k - 15;
        float a1 = (gi2>=0 && gi2<400) ? aw_s[gi2] : 0.f;
        float a2 = (gi2>=0 && gi2<400) ? awc_s[gi2] : 0.f;
        cf0 += wc_s[(f0+0)*62+k]*a1 + wc_s[(f0+0)*62+31+k]*a2;
        cf1 += wc_s[(f0+1)*62+k]*a1 + wc_s[(f0+1)*62+31+k]*a2;
        cf2 += wc_s[(f0+2)*62+k]*a1 + wc_s[(f0+2)*62+31+k]*a2;
        cf3 += wc_s[(f0+3)*62+k]*a1 + wc_s[(f0+3)*62+31+k]*a2;
      }
      loc[tl*33+f0+0]=cf0; loc[tl*33+f0+1]=cf1;
      loc[tl*33+f0+2]=cf2; loc[tl*33+f0+3]=cf3;
    }
  }
  __syncthreads();
  { int tl = tid & 63, as = tid >> 6;
    if (tl < 50){
      int tg = t0 + tl;
      float e = 0.f;
      const float* lrow = loc + tl*33;
      for (int aa=0; aa<16; aa++){
        int a = as*16 + aa;
        float pmv = pmT[(size_t)b*51200 + (size_t)a*400 + tg];
        float lv = 0.f;
        #pragma unroll
        for (int f=0; f<32; f++) lv += lrow[f]*wd_s[f*128+a];
        e += ftanh(q_s[a]+pmv+lv)*v_s[a];
      }
      ep[as*64+tl] = e;
    }
  }
  __syncthreads();
  if (tid < 50){
    int tg = t0 + tid;
    float ee=0.f;
    #pragma unroll
    for (int as2=0; as2<8; as2++) ee += ep[as2*64+tid];
    stf(E + b*400 + tg, (tg < mlen[b]) ? ee : -1e30f);
  }
}

// -------------------- C: softmax + ctx + proj(t-1) --------------------
__device__ __forceinline__ void c_phase(float* sm, const float* E, const float* memory,
    float* AWw, const float* AWCr, float* AWCw,
    float* CTXw, const float* CTXpp, const float* DH,
    const float* proj_W, const float* proj_b,
    const float* gate_W, const float* gate_b,
    float* out, float* aligns, int step)
{
  float* e_s = sm;           // 400
  float* red = sm+400;       // 16
  float* cp  = sm+416;       // 512
  float* do_s= sm+928;       // 1536
  float* pps = sm+2464;      // 486
  const int bid = blockIdx.x, tid = threadIdx.x;
  const int b = bid & 31, yD = bid >> 5;

  float ev = (tid<400) ? ldf(E+b*400+tid) : -1e30f;
  float m = ev;
  for (int off=32; off>0; off>>=1) m = fmaxf(m, __shfl_down(m, off, 64));
  if ((tid&63)==0) red[tid>>6]=m;
  __syncthreads();
  if (tid==0){ float mm=red[0]; for (int i=1;i<8;i++) mm=fmaxf(mm,red[i]); red[8]=mm; }
  __syncthreads();
  m = red[8];
  float ex = (tid<400) ? __expf(ev-m) : 0.f;
  float ss = ex;
  for (int off=32; off>0; off>>=1) ss += __shfl_down(ss, off, 64);
  if ((tid&63)==0) red[tid>>6]=ss;
  __syncthreads();
  if (tid==0){ float s2=0.f; for (int i=0;i<8;i++) s2+=red[i]; red[9]=1.f/s2; }
  __syncthreads();
  float anew = ex*red[9];
  if (tid<400) e_s[tid]=anew;
  if (yD==0 && tid<400){
    stf(AWw+b*400+tid, anew);
    stf(AWCw+b*400+tid, ldf(AWCr+b*400+tid) + anew);
    aligns[(size_t)b*160000 + (size_t)step*400 + tid] = anew;
  }
  __syncthreads();
  { int d = tid & 63, ts = tid >> 6;
    const int d0 = yD*64;
    const float* mrow = memory + (size_t)b*204800 + d0 + d;
    float pacc=0.f;
    for (int tt=ts*50; tt<ts*50+50; tt++) pacc += e_s[tt]*mrow[(size_t)tt*512];
    cp[ts*64+d]=pacc; }
  __syncthreads();
  if (tid<64){
    float s2=0.f;
    #pragma unroll
    for (int ts2=0; ts2<8; ts2++) s2+=cp[ts2*64+tid];
    stf(CTXw + b*512 + yD*64 + tid, s2);
  }
  if (yD==0 && step>0){
    for (int i=tid; i<1536; i+=NTHR)
      do_s[i] = (i<1024) ? ldf(DH+b*1024+i) : ldf(CTXpp+b*512 + (i-1024));
    __syncthreads();
    int sl = tid/81, o = tid - sl*81;
    if (sl < 6){
      float s=0.f; int kb = sl*256;
      for (int k=kb;k<kb+256;k++){
        float w2 = (o<80) ? proj_W[k*80+o] : gate_W[k];
        s += do_s[k]*w2;
      }
      pps[sl*81+o]=s;
    }
    __syncthreads();
    if (tid<81){
      float r=0.f;
      #pragma unroll
      for (int s2=0;s2<6;s2++) r += pps[s2*81+tid];
      if (tid<80) out[(size_t)b*32000 + tid*400 + (step-1)] = r + proj_b[tid];
      else        out[1024000 + b*400 + (step-1)] = r + gate_b[0];
    }
  }
}

// -------------------- epilogue: dec step 399 --------------------
__device__ __forceinline__ void dec_final_phase(float* sm,
    const float* Gd, const float* dec_b,
    const float* DC, const float* CTX1,
    const float* proj_W, const float* proj_b,
    const float* gate_W, const float* gate_b, float* out)
{
  float* do_s = sm;       // 1536
  float* pps  = sm+1536;  // 486
  const int b = blockIdx.x, tid = threadIdx.x;
  for (int u0=0; u0<2; u0++){
    int u = tid + u0*512;
    float g4[4];
    #pragma unroll
    for (int g=0; g<4; g++){
      float s = dec_b[g*1024 + u];
      #pragma unroll
      for (int sl=0; sl<8; sl++)
        s += ldf(Gd + (size_t)sl*131072 + (size_t)b*4096 + g*1024 + u);
      g4[g] = s;
    }
    float c = sigm(g4[1])*ldf(DC + b*1024 + u) + sigm(g4[0])*ftanh(g4[2]);
    do_s[u] = sigm(g4[3])*ftanh(c);
  }
  do_s[1024+tid] = ldf(CTX1 + b*512 + tid);
  __syncthreads();
  int sl = tid/81, o = tid - sl*81;
  if (sl < 6){
    float s=0.f; int kb = sl*256;
    for (int k=kb;k<kb+256;k++){
      float w2 = (o<80) ? proj_W[k*80+o] : gate_W[k];
      s += do_s[k]*w2;
    }
    pps[sl*81+o]=s;
  }
  __syncthreads();
  if (tid<81){
    float r=0.f;
    #pragma unroll
    for (int s2=0;s2<6;s2++) r += pps[s2*81+tid];
    if (tid<80) out[(size_t)b*32000 + tid*400 + 399] = r + proj_b[tid];
    else        out[1024000 + b*400 + 399] = r + gate_b[0];
  }
}

// -------------------- persistent cooperative kernel --------------------
__global__ void __launch_bounds__(NTHR) decoder_persist(
    const float* memory, const int* mlen, const float* query_W,
    const float* wcv, const float* wdv, const float* vvec,
    const float* att_Wih, const float* att_Whh, const float* att_b,
    const float* dec_Wih, const float* dec_Whh, const float* dec_b,
    const float* proj_W, const float* proj_b,
    const float* gate_W, const float* gate_b,
    float* ws, float* out)
{
  extern __shared__ float sm[];
  float* PRE  = ws + OFF_PRE;
  float* PMT  = ws + OFF_PMT;
  float* GATT = ws + OFF_GATT;
  float* GDEC = ws + OFF_GDEC;
  float* E    = ws + OFF_E;
  float* QP   = ws + OFF_QP;
  float* AH   = ws + OFF_AH;
  float* AC_[2] = { ws + OFF_AC0, ws + OFF_AC1 };
  float* DH   = ws + OFF_DH;
  float* DC   = ws + OFF_DC;
  float* AW_[2] = { ws + OFF_AW0, ws + OFF_AW1 };
  float* AWC_[2]= { ws + OFF_AWC0, ws + OFF_AWC1 };
  float* CTX_[2]= { ws + OFF_CTX0, ws + OFF_CTX1 };
  unsigned* bar = (unsigned*)(ws + OFF_BAR);
  float* aligns = out + 1036800;

  // prologue: GATT(0) from zero state
  w_phase(sm, PRE, CTX_[1], AH, DH, att_Wih, att_Whh, GATT,
          dec_Wih, dec_Whh, GDEC, true, false);
  gsync(bar);

  for (int t=0; t<400; t++){
    const int p = t & 1, pp = 1 - p;
    // B1: att reduce+pw+q halves; dec pw of t-1
    b1_phase(sm, GATT, GDEC, att_b, dec_b, query_W,
             AH, AC_[pp], AC_[p], DH, DC, QP, t);
    gsync(bar);
    // B2: conv + energies
    b2_phase(sm, wcv, wdv, vvec, PMT, mlen, AW_[pp], AWC_[pp], QP, E);
    gsync(bar);
    // C: softmax + ctx + proj(t-1)
    c_phase(sm, E, memory, AW_[p], AWC_[pp], AWC_[p], CTX_[p], CTX_[pp],
            DH, proj_W, proj_b, gate_W, gate_b, out, aligns, t);
    gsync(bar);
    // W: GATT(t+1) [skip at 399] + GDEC(t)
    w_phase(sm, (t<399) ? (PRE + (size_t)(t+1)*8192) : PRE, CTX_[p], AH, DH,
            att_Wih, att_Whh, GATT, dec_Wih, dec_Whh, GDEC, t<399, true);
    gsync(bar);
  }
  if (blockIdx.x < 32)
    dec_final_phase(sm, GDEC, dec_b, DC, CTX_[1],
                    proj_W, proj_b, gate_W, gate_b, out);
}

// -------------------- launch --------------------

extern "C" void kernel_launch(void* const* d_in, const int* in_sizes, int n_in,
                              void* d_out, int out_size, void* d_ws, size_t ws_size,
                              hipStream_t stream) {
  const float* memory      = (const float*)d_in[0];
  const float* mel_target  = (const float*)d_in[1];
  const int*   mlen        = (const int*)  d_in[2];
  const float* prenet_W1   = (const float*)d_in[3];
  const float* prenet_W2   = (const float*)d_in[4];
  const float* query_W     = (const float*)d_in[5];
  const float* memory_W    = (const float*)d_in[6];
  const float* weight_vec  = (const float*)d_in[7];
  const float* loc_conv_W  = (const float*)d_in[8];
  const float* loc_dense_W = (const float*)d_in[9];
  const float* att_Wih     = (const float*)d_in[10];
  const float* att_Whh     = (const float*)d_in[11];
  const float* att_b       = (const float*)d_in[12];
  const float* dec_Wih     = (const float*)d_in[13];
  const float* dec_Whh     = (const float*)d_in[14];
  const float* dec_b       = (const float*)d_in[15];
  const float* proj_W      = (const float*)d_in[16];
  const float* proj_b      = (const float*)d_in[17];
  const float* gate_W      = (const float*)d_in[18];
  const float* gate_b      = (const float*)d_in[19];
  float* out = (float*)d_out;
  float* ws  = (float*)d_ws;

  float* PRE = ws + OFF_PRE;
  float* PMT = ws + OFF_PMT;

  // zero the entire used workspace every call -> replay-deterministic
  hipLaunchKernelGGL(zero_kernel, dim3((WS_TOTAL+255u)/256u), dim3(256), 0, stream, ws, WS_TOTAL);
  hipLaunchKernelGGL(prenet_kernel, dim3(12800), dim3(256), 0, stream,
                     mel_target, prenet_W1, prenet_W2, PRE);
  hipLaunchKernelGGL(pm_kernel, dim3(12800), dim3(128), 0, stream, memory, memory_W, PMT);

  void* args[] = {
    (void*)&memory, (void*)&mlen, (void*)&query_W,
    (void*)&loc_conv_W, (void*)&loc_dense_W, (void*)&weight_vec,
    (void*)&att_Wih, (void*)&att_Whh, (void*)&att_b,
    (void*)&dec_Wih, (void*)&dec_Whh, (void*)&dec_b,
    (void*)&proj_W, (void*)&proj_b, (void*)&gate_W, (void*)&gate_b,
    (void*)&ws, (void*)&out
  };
  hipLaunchCooperativeKernel((const void*)decoder_persist, dim3(NBLK), dim3(NTHR),
                             args, LDS_FLOATS*sizeof(float), stream);
}